// Round 2
// baseline (842.084 us; speedup 1.0000x reference)
//
#include <hip/hip_runtime.h>
#include <hip/hip_bf16.h>

#define BB 16
#define NN 1024
#define FF 128
#define HH 192
#define NROWS (BB*NN)
#define MAXC 128
#define EPSV 1e-5f

// workspace layout, in float (4B) units
constexpr size_t OFF_H0  = 0;                                  // [NROWS*HH] f32
constexpr size_t OFF_Z   = OFF_H0 + (size_t)NROWS*HH;          // [NROWS*HH] f32
constexpr size_t OFF_DIS = OFF_Z  + (size_t)NROWS*HH;          // [NROWS] f32
constexpr size_t OFF_G   = OFF_DIS + NROWS;                    // [BB*HH] f32
constexpr size_t OFF_ST  = OFF_G + BB*HH;                      // 4 stages * 2 * 256 f32
constexpr size_t OFF_FLAG= OFF_ST + 4*2*256;                   // 1 int (1 => inputs f32)
constexpr size_t OFF_CNT = OFF_FLAG + 1;                       // [NROWS] int32
constexpr size_t OFF_COLS= OFF_CNT + NROWS;                    // [NROWS*MAXC] u16

static __device__ __forceinline__ float bf(const __hip_bfloat16 v) {
    return __bfloat162float(v);
}
static __device__ __forceinline__ float ldin(const void* p, size_t i, int isf) {
    return isf ? ((const float*)p)[i]
               : __bfloat162float(((const __hip_bfloat16*)p)[i]);
}

// Detect input dtype from adj bit patterns + zero BN-stat accumulators.
// adj elements are exactly {0.0,1.0}. As f32 words the low 16 bits are never
// 0x3F80; as packed bf16 an even-index 1.0 element gives low-half 0x3F80.
__global__ void detect_and_zero(const unsigned int* __restrict__ adjw, float* ws) {
    __shared__ int evid;
    int tid = threadIdx.x;
    if (tid == 0) evid = 0;
    __syncthreads();
    int local = 0;
    for (int k = tid; k < 16384; k += 256) {
        unsigned int w = adjw[k];
        if ((w & 0xFFFFu) == 0x3F80u) local++;
    }
    if (local) atomicAdd(&evid, local);
    for (int k = tid; k < 4*2*256; k += 256) ws[OFF_ST + k] = 0.f;
    __syncthreads();
    if (tid == 0) ((int*)ws)[OFF_FLAG] = (evid == 0) ? 1 : 0;
}

// One block (256 thr) per adjacency row: neighbor list + dis = rsqrt(deg).
__global__ void build_graph(const void* __restrict__ adj, float* ws) {
    int row = blockIdx.x;
    int i   = row & (NN - 1);
    int tid = threadIdx.x;
    const int isf = ((const int*)ws)[OFF_FLAG];
    __shared__ int cnt_s;
    __shared__ unsigned short colbuf[MAXC];
    if (tid == 0) cnt_s = 0;
    __syncthreads();
    if (isf) {
        const float* ar = (const float*)adj + (size_t)row * NN;
        for (int j = tid; j < NN; j += 256) {
            if (ar[j] != 0.f || j == i) {
                int p = atomicAdd(&cnt_s, 1);
                if (p < MAXC) colbuf[p] = (unsigned short)j;
            }
        }
    } else {
        const __hip_bfloat16* ar = (const __hip_bfloat16*)adj + (size_t)row * NN;
        for (int j = tid; j < NN; j += 256) {
            if (bf(ar[j]) != 0.f || j == i) {
                int p = atomicAdd(&cnt_s, 1);
                if (p < MAXC) colbuf[p] = (unsigned short)j;
            }
        }
    }
    __syncthreads();
    int c = cnt_s; if (c > MAXC) c = MAXC;
    int* cnt = (int*)(ws + OFF_CNT);
    unsigned short* cols = (unsigned short*)(ws + OFF_COLS);
    if (tid == 0) {
        cnt[row] = c;
        ws[OFF_DIS + row] = rsqrtf((float)cnt_s);   // deg >= 1 (self loop)
    }
    for (int k = tid; k < c; k += 256) cols[(size_t)row*MAXC + k] = colbuf[k];
}

// Per-feature sum/sumsq of x. 256 blocks x 128 thr (thread = feature).
__global__ void stats_x(const void* __restrict__ x, float* ws) {
    int tid = threadIdx.x;
    int r0  = blockIdx.x * (NROWS/256);
    const int isf = ((const int*)ws)[OFF_FLAG];
    float s = 0.f, sq = 0.f;
    if (isf) {
        const float* xp = (const float*)x;
        for (int r = 0; r < NROWS/256; ++r) {
            float v = xp[(size_t)(r0 + r)*FF + tid];
            s += v; sq += v*v;
        }
    } else {
        const __hip_bfloat16* xp = (const __hip_bfloat16*)x;
        for (int r = 0; r < NROWS/256; ++r) {
            float v = bf(xp[(size_t)(r0 + r)*FF + tid]);
            s += v; sq += v*v;
        }
    }
    float* st = ws + OFF_ST;          // stage 0
    atomicAdd(&st[tid], s);
    atomicAdd(&st[256 + tid], sq);
}

// h0 = relu( BN(x) @ W_feat ).  One block (192 thr) per row.
__global__ void feat_mm(const void* __restrict__ x,
                        const void* __restrict__ gg,
                        const void* __restrict__ bb,
                        const void* __restrict__ W,
                        float* ws) {
    int row = blockIdx.x, tid = threadIdx.x;
    const int isf = ((const int*)ws)[OFF_FLAG];
    __shared__ float xn[FF];
    const float* st = ws + OFF_ST;
    if (tid < FF) {
        float m   = st[tid] * (1.f/NROWS);
        float var = st[256+tid] * (1.f/NROWS) - m*m;
        float rs  = rsqrtf(var + EPSV);
        float a   = ldin(gg, tid, isf) * rs;
        float c   = ldin(bb, tid, isf) - m * a;
        xn[tid] = ldin(x, (size_t)row*FF + tid, isf) * a + c;
    }
    __syncthreads();
    float acc = 0.f;
    if (isf) {
        const float* Wp = (const float*)W;
        for (int f = 0; f < FF; ++f) acc += xn[f] * Wp[f*HH + tid];
    } else {
        const __hip_bfloat16* Wp = (const __hip_bfloat16*)W;
        for (int f = 0; f < FF; ++f) acc += xn[f] * bf(Wp[f*HH + tid]);
    }
    ws[OFF_H0 + (size_t)row*HH + tid] = fmaxf(acc, 0.f);
}

// Per-channel sum/sumsq of h (f32 in ws). 64 blocks x 192 thr.
__global__ void stats_h(const float* __restrict__ h, float* ws, int stage) {
    int tid = threadIdx.x;
    int r0  = blockIdx.x * (NROWS/64);
    float s = 0.f, sq = 0.f;
    for (int r = 0; r < NROWS/64; ++r) {
        float v = h[(size_t)(r0 + r)*HH + tid];
        s += v; sq += v*v;
    }
    float* st = ws + OFF_ST + (size_t)stage*512;
    atomicAdd(&st[tid], s);
    atomicAdd(&st[256 + tid], sq);
}

// z = BN(h) @ convs_W[layer].  One block (192 thr) per row.
// gg/bb/W are BASE pointers; per-layer offsets computed in elements here
// (host cannot offset without knowing dtype).
__global__ void mm_bn(const float* __restrict__ h,
                      const void* __restrict__ gg,
                      const void* __restrict__ bb,
                      const void* __restrict__ W,
                      float* __restrict__ z,
                      int layer, float* ws) {
    int row = blockIdx.x, tid = threadIdx.x;
    const int isf = ((const int*)ws)[OFF_FLAG];
    const float* st = ws + OFF_ST + (size_t)(1 + layer)*512;
    __shared__ float hn[HH];
    float m   = st[tid] * (1.f/NROWS);
    float var = st[256+tid] * (1.f/NROWS) - m*m;
    float rs  = rsqrtf(var + EPSV);
    float a   = ldin(gg, (size_t)layer*HH + tid, isf) * rs;
    float c   = ldin(bb, (size_t)layer*HH + tid, isf) - m * a;
    hn[tid] = h[(size_t)row*HH + tid] * a + c;
    __syncthreads();
    float acc = 0.f;
    size_t w0 = (size_t)layer*HH*HH;
    if (isf) {
        const float* Wp = (const float*)W + w0;
        for (int k = 0; k < HH; ++k) acc += hn[k] * Wp[k*HH + tid];
    } else {
        const __hip_bfloat16* Wp = (const __hip_bfloat16*)W + w0;
        for (int k = 0; k < HH; ++k) acc += hn[k] * bf(Wp[k*HH + tid]);
    }
    z[(size_t)row*HH + tid] = acc;
}

// hout = relu( dis_i * sum_j dis_j * z_j + bias[layer] ). One block (192 thr)/row.
__global__ void spmm(const float* __restrict__ z, const void* __restrict__ bias,
                     float* __restrict__ hout, int layer, float* ws) {
    int row = blockIdx.x, tid = threadIdx.x;
    const int isf = ((const int*)ws)[OFF_FLAG];
    const float* dis = ws + OFF_DIS;
    const int* cnt   = (const int*)(ws + OFF_CNT);
    const unsigned short* cl = (const unsigned short*)(ws + OFF_COLS) + (size_t)row*MAXC;
    int b = row >> 10;
    int c = cnt[row];
    float acc = 0.f;
    for (int k = 0; k < c; ++k) {
        int jr = (b << 10) + (int)cl[k];
        acc += dis[jr] * z[(size_t)jr*HH + tid];
    }
    float o = dis[row]*acc + ldin(bias, (size_t)layer*HH + tid, isf);
    hout[(size_t)row*HH + tid] = fmaxf(o, 0.f);
}

// g[b,c] = mean over N of h.  16 blocks x 192 thr.
__global__ void pool(const float* __restrict__ h, float* __restrict__ g) {
    int b = blockIdx.x, tid = threadIdx.x;
    float acc = 0.f;
    for (int n = 0; n < NN; ++n)
        acc += h[((size_t)(b*NN + n))*HH + tid];
    g[b*HH + tid] = acc * (1.f/NN);
}

// BN -> relu(linear) -> BN -> classifier -> log_softmax. One block, 256 thr.
__global__ void tail(const float* __restrict__ g,
                     const void* __restrict__ fc_g,  const void* __restrict__ fc_b,
                     const void* __restrict__ lin_W, const void* __restrict__ lin_b,
                     const void* __restrict__ hid_g, const void* __restrict__ hid_b,
                     const void* __restrict__ cls_W, const void* __restrict__ cls_b,
                     void* __restrict__ out, const float* ws) {
    __shared__ float g1[BB][HH];
    __shared__ float g2[BB][HH];
    __shared__ float logits[BB][10];
    __shared__ float lse[BB];
    int tid = threadIdx.x;
    const int isf = ((const int*)ws)[OFF_FLAG];
    if (tid < HH) {
        float s = 0.f, sq = 0.f;
        for (int b = 0; b < BB; ++b) { float v = g[b*HH + tid]; s += v; sq += v*v; }
        float m = s*(1.f/BB), var = sq*(1.f/BB) - m*m;
        float rs = rsqrtf(var + EPSV);
        float a = ldin(fc_g, tid, isf) * rs;
        float c = ldin(fc_b, tid, isf) - m*a;
        for (int b = 0; b < BB; ++b) g1[b][tid] = g[b*HH + tid]*a + c;
    }
    __syncthreads();
    if (tid < HH) {
        if (isf) {
            const float* Wp = (const float*)lin_W;
            for (int b = 0; b < BB; ++b) {
                float acc = ldin(lin_b, tid, isf);
                for (int h = 0; h < HH; ++h) acc += g1[b][h] * Wp[h*HH + tid];
                g2[b][tid] = fmaxf(acc, 0.f);
            }
        } else {
            const __hip_bfloat16* Wp = (const __hip_bfloat16*)lin_W;
            for (int b = 0; b < BB; ++b) {
                float acc = ldin(lin_b, tid, isf);
                for (int h = 0; h < HH; ++h) acc += g1[b][h] * bf(Wp[h*HH + tid]);
                g2[b][tid] = fmaxf(acc, 0.f);
            }
        }
    }
    __syncthreads();
    if (tid < HH) {
        float s = 0.f, sq = 0.f;
        for (int b = 0; b < BB; ++b) { float v = g2[b][tid]; s += v; sq += v*v; }
        float m = s*(1.f/BB), var = sq*(1.f/BB) - m*m;
        float rs = rsqrtf(var + EPSV);
        float a = ldin(hid_g, tid, isf) * rs;
        float c = ldin(hid_b, tid, isf) - m*a;
        for (int b = 0; b < BB; ++b) g2[b][tid] = g2[b][tid]*a + c;
    }
    __syncthreads();
    if (tid < BB*10) {
        int b = tid/10, k = tid%10;
        float acc = ldin(cls_b, k, isf);
        if (isf) {
            const float* Wp = (const float*)cls_W;
            for (int h = 0; h < HH; ++h) acc += g2[b][h] * Wp[h*10 + k];
        } else {
            const __hip_bfloat16* Wp = (const __hip_bfloat16*)cls_W;
            for (int h = 0; h < HH; ++h) acc += g2[b][h] * bf(Wp[h*10 + k]);
        }
        logits[b][k] = acc;
    }
    __syncthreads();
    if (tid < BB) {
        float m = -1e30f;
        for (int k = 0; k < 10; ++k) m = fmaxf(m, logits[tid][k]);
        float s = 0.f;
        for (int k = 0; k < 10; ++k) s += expf(logits[tid][k] - m);
        lse[tid] = m + logf(s);
    }
    __syncthreads();
    if (tid < BB*10) {
        int b = tid/10;
        float v = logits[b][tid%10] - lse[b];
        if (isf) ((float*)out)[tid] = v;
        else     ((__hip_bfloat16*)out)[tid] = __float2bfloat16(v);
    }
}

extern "C" void kernel_launch(void* const* d_in, const int* in_sizes, int n_in,
                              void* d_out, int out_size, void* d_ws, size_t ws_size,
                              hipStream_t stream) {
    const void* x       = d_in[0];
    const void* adj     = d_in[1];
    const void* bnf_g   = d_in[2];
    const void* bnf_b   = d_in[3];
    const void* W_feat  = d_in[4];
    const void* bnc_g   = d_in[5];
    const void* bnc_b   = d_in[6];
    const void* convs_W = d_in[7];
    const void* convs_b = d_in[8];
    const void* fc_g    = d_in[9];
    const void* fc_b    = d_in[10];
    const void* lin_W   = d_in[11];
    const void* lin_b   = d_in[12];
    const void* hid_g   = d_in[13];
    const void* hid_b   = d_in[14];
    const void* cls_W   = d_in[15];
    const void* cls_b   = d_in[16];

    float* ws  = (float*)d_ws;
    float* H0  = ws + OFF_H0;
    float* Z   = ws + OFF_Z;

    detect_and_zero<<<1, 256, 0, stream>>>((const unsigned int*)adj, ws);
    build_graph<<<NROWS, 256, 0, stream>>>(adj, ws);
    stats_x<<<256, FF, 0, stream>>>(x, ws);
    feat_mm<<<NROWS, HH, 0, stream>>>(x, bnf_g, bnf_b, W_feat, ws);
    for (int l = 0; l < 3; ++l) {
        stats_h<<<64, HH, 0, stream>>>(H0, ws, 1 + l);
        mm_bn<<<NROWS, HH, 0, stream>>>(H0, bnc_g, bnc_b, convs_W, Z, l, ws);
        spmm<<<NROWS, HH, 0, stream>>>(Z, convs_b, H0, l, ws);
    }
    pool<<<BB, HH, 0, stream>>>(H0, ws + OFF_G);
    tail<<<1, 256, 0, stream>>>(ws + OFF_G, fc_g, fc_b, lin_W, lin_b,
                                hid_g, hid_b, cls_W, cls_b, d_out, ws);
}

// Round 3
// 445.528 us; speedup vs baseline: 1.8901x; 1.8901x over previous
//
#include <hip/hip_runtime.h>
#include <hip/hip_bf16.h>

#define BB 16
#define NN 1024
#define FF 128
#define HH 192
#define NROWS (BB*NN)
#define MAXC 128
#define EPSV 1e-5f

// workspace layout, in float (4B) units. Total ~34 MB (R1 used 42 MB fine).
constexpr size_t OFF_H0  = 0;                                  // [NROWS*HH] f32
constexpr size_t OFF_ZB  = OFF_H0 + (size_t)NROWS*HH;          // [NROWS*HH] bf16 (Z' = dis_j * BN(h)W)
constexpr size_t OFF_HB  = OFF_ZB + (size_t)NROWS*HH/2;        // [NROWS*HH] bf16 (BN(h) cast, GEMM A)
constexpr size_t OFF_XN  = OFF_HB + (size_t)NROWS*HH/2;        // [NROWS*FF] bf16 (BN(x) cast)
constexpr size_t OFF_WT  = OFF_XN + (size_t)NROWS*FF/2;        // bf16: WfeatT[192*128] + WcT[3][192*192]
constexpr size_t OFF_DIS = OFF_WT + (192*128 + 3*192*192)/2;   // [NROWS] f32
constexpr size_t OFF_G   = OFF_DIS + NROWS;                    // [BB*HH] f32 (pool sums, atomics)
constexpr size_t OFF_ST  = OFF_G + BB*HH;                      // 4 stages * 2 * 256 f32
constexpr size_t OFF_FLAG= OFF_ST + 4*2*256;                   // 1 int (1 => inputs f32)
constexpr size_t OFF_CNT = OFF_FLAG + 1;                       // [NROWS] int32
constexpr size_t OFF_COLS= OFF_CNT + NROWS;                    // [NROWS*MAXC] u16

constexpr int WT_FEAT = 0;              // bf16-elem offset of WfeatT [192][128]
constexpr int WT_CONV = 192*128;        // bf16-elem offset of WcT[l] [192][192]

typedef __attribute__((ext_vector_type(8))) short short8;   // 8 bf16 in 4 VGPRs
typedef __attribute__((ext_vector_type(4))) float f32x4;

static __device__ __forceinline__ float bf(const __hip_bfloat16 v) {
    return __bfloat162float(v);
}
static __device__ __forceinline__ float ldin(const void* p, size_t i, int isf) {
    return isf ? ((const float*)p)[i]
               : __bfloat162float(((const __hip_bfloat16*)p)[i]);
}

// Detect input dtype from adj bit patterns; zero BN-stat accumulators + pool sums.
__global__ void detect_and_zero(const unsigned int* __restrict__ adjw, float* ws) {
    __shared__ int evid;
    int tid = threadIdx.x;
    if (tid == 0) evid = 0;
    __syncthreads();
    int local = 0;
    for (int k = tid; k < 16384; k += 256) {
        unsigned int w = adjw[k];
        if ((w & 0xFFFFu) == 0x3F80u) local++;   // bf16-packed even-index 1.0
    }
    if (local) atomicAdd(&evid, local);
    for (int k = tid; k < 4*2*256; k += 256) ws[OFF_ST + k] = 0.f;
    for (int k = tid; k < BB*HH; k += 256) ws[OFF_G + k] = 0.f;
    __syncthreads();
    if (tid == 0) ((int*)ws)[OFF_FLAG] = (evid == 0) ? 1 : 0;
}

// One block (256 thr) per adjacency row: neighbor list + dis = rsqrt(deg).
__global__ void build_graph(const void* __restrict__ adj, float* ws) {
    int row = blockIdx.x;
    int i   = row & (NN - 1);
    int tid = threadIdx.x;
    const int isf = ((const int*)ws)[OFF_FLAG];
    __shared__ int cnt_s;
    __shared__ unsigned short colbuf[MAXC];
    if (tid == 0) cnt_s = 0;
    __syncthreads();
    if (isf) {
        const float* ar = (const float*)adj + (size_t)row * NN;
        for (int j = tid; j < NN; j += 256) {
            if (ar[j] != 0.f || j == i) {
                int p = atomicAdd(&cnt_s, 1);
                if (p < MAXC) colbuf[p] = (unsigned short)j;
            }
        }
    } else {
        const __hip_bfloat16* ar = (const __hip_bfloat16*)adj + (size_t)row * NN;
        for (int j = tid; j < NN; j += 256) {
            if (bf(ar[j]) != 0.f || j == i) {
                int p = atomicAdd(&cnt_s, 1);
                if (p < MAXC) colbuf[p] = (unsigned short)j;
            }
        }
    }
    __syncthreads();
    int c = cnt_s; if (c > MAXC) c = MAXC;
    if (tid == 0) {
        ((int*)(ws + OFF_CNT))[row] = c;
        ws[OFF_DIS + row] = rsqrtf((float)cnt_s);   // deg >= 1 (self loop)
    }
    unsigned short* cols = (unsigned short*)(ws + OFF_COLS);
    for (int k = tid; k < c; k += 256) cols[(size_t)row*MAXC + k] = colbuf[k];
}

// Transpose + bf16-cast weights. grid 768 x 192thr; block b: matrix b/192, out-row b%192.
__global__ void prep_wt(const void* __restrict__ W_feat, const void* __restrict__ convs_W,
                        float* ws) {
    const int isf = ((const int*)ws)[OFF_FLAG];
    __hip_bfloat16* wt = (__hip_bfloat16*)(ws + OFF_WT);
    int n   = blockIdx.x % HH;
    int mi  = blockIdx.x / HH;    // 0 = feat, 1..3 = conv layer
    int tid = threadIdx.x;
    if (mi == 0) {
        if (tid < FF)
            wt[WT_FEAT + n*FF + tid] =
                __float2bfloat16(ldin(W_feat, (size_t)tid*HH + n, isf));
    } else {
        int l = mi - 1;
        wt[WT_CONV + (size_t)l*HH*HH + (size_t)n*HH + tid] =
            __float2bfloat16(ldin(convs_W, (size_t)l*HH*HH + (size_t)tid*HH + n, isf));
    }
}

// Per-feature sum/sumsq of x. 256 blocks x 128 thr (thread = feature).
__global__ void stats_x(const void* __restrict__ x, float* ws) {
    int tid = threadIdx.x;
    int r0  = blockIdx.x * (NROWS/256);
    const int isf = ((const int*)ws)[OFF_FLAG];
    float s = 0.f, sq = 0.f;
    if (isf) {
        const float* xp = (const float*)x;
        for (int r = 0; r < NROWS/256; ++r) {
            float v = xp[(size_t)(r0 + r)*FF + tid];
            s += v; sq += v*v;
        }
    } else {
        const __hip_bfloat16* xp = (const __hip_bfloat16*)x;
        for (int r = 0; r < NROWS/256; ++r) {
            float v = bf(xp[(size_t)(r0 + r)*FF + tid]);
            s += v; sq += v*v;
        }
    }
    float* st = ws + OFF_ST;
    atomicAdd(&st[tid], s);
    atomicAdd(&st[256 + tid], sq);
}

// Xn = bf16( BN(x) ). grid 8192 x 256thr (2 rows of 128 per block).
__global__ void bn_cast_x(const void* __restrict__ x,
                          const void* __restrict__ gg, const void* __restrict__ bb,
                          float* ws) {
    int tid = threadIdx.x;
    int ch  = tid & (FF - 1);
    const int isf = ((const int*)ws)[OFF_FLAG];
    const float* st = ws + OFF_ST;
    float m   = st[ch] * (1.f/NROWS);
    float var = st[256+ch] * (1.f/NROWS) - m*m;
    float a   = ldin(gg, ch, isf) * rsqrtf(var + EPSV);
    float c   = ldin(bb, ch, isf) - m*a;
    size_t i  = (size_t)blockIdx.x*256 + tid;
    ((__hip_bfloat16*)(ws + OFF_XN))[i] = __float2bfloat16(ldin(x, i, isf)*a + c);
}

// Per-channel sum/sumsq of h (f32). 64 blocks x 192 thr.
__global__ void stats_h(const float* __restrict__ h, float* ws, int stage) {
    int tid = threadIdx.x;
    int r0  = blockIdx.x * (NROWS/64);
    float s = 0.f, sq = 0.f;
    for (int r = 0; r < NROWS/64; ++r) {
        float v = h[(size_t)(r0 + r)*HH + tid];
        s += v; sq += v*v;
    }
    float* st = ws + OFF_ST + (size_t)stage*512;
    atomicAdd(&st[tid], s);
    atomicAdd(&st[256 + tid], sq);
}

// Hb = bf16( BN(h) ) for layer. grid 4096 x 192thr (4 rows/block).
__global__ void bn_cast_h(const float* __restrict__ h,
                          const void* __restrict__ gg, const void* __restrict__ bb,
                          int layer, float* ws) {
    int tid = threadIdx.x;
    const int isf = ((const int*)ws)[OFF_FLAG];
    const float* st = ws + OFF_ST + (size_t)(1 + layer)*512;
    float m   = st[tid] * (1.f/NROWS);
    float var = st[256+tid] * (1.f/NROWS) - m*m;
    float a   = ldin(gg, (size_t)layer*HH + tid, isf) * rsqrtf(var + EPSV);
    float c   = ldin(bb, (size_t)layer*HH + tid, isf) - m*a;
    __hip_bfloat16* hb = (__hip_bfloat16*)(ws + OFF_HB);
    size_t r0 = (size_t)blockIdx.x*4;
    #pragma unroll
    for (int rr = 0; rr < 4; ++rr)
        hb[(r0+rr)*HH + tid] = __float2bfloat16(h[(r0+rr)*HH + tid]*a + c);
}

// C = A[M x K] @ BT[N x K]^T via MFMA 16x16x32 bf16. Block 256thr = 4 waves,
// wave owns 16 rows x 192 cols (12 n-tiles). grid = NROWS/64.
// MODE 0: H0 = relu(C) f32.  MODE 1: Z' = bf16(dis[row] * C).
template<int K, int MODE>
__global__ __launch_bounds__(256) void gemm_mfma(const __hip_bfloat16* __restrict__ A,
                                                 const __hip_bfloat16* __restrict__ BT,
                                                 float* __restrict__ ws) {
    int lane = threadIdx.x & 63, w = threadIdx.x >> 6;
    int row0 = blockIdx.x*64 + w*16;
    int m    = lane & 15, quad = lane >> 4;
    f32x4 acc[12];
    #pragma unroll
    for (int t = 0; t < 12; ++t) acc[t] = f32x4{0.f,0.f,0.f,0.f};
    #pragma unroll
    for (int kb = 0; kb < K/32; ++kb) {
        short8 a = *(const short8*)(A + (size_t)(row0+m)*K + kb*32 + quad*8);
        #pragma unroll
        for (int t = 0; t < 12; ++t) {
            short8 b = *(const short8*)(BT + (size_t)(t*16+m)*K + kb*32 + quad*8);
            acc[t] = __builtin_amdgcn_mfma_f32_16x16x32_bf16(a, b, acc[t], 0, 0, 0);
        }
    }
    if (MODE == 0) {
        float* H0 = ws + OFF_H0;
        #pragma unroll
        for (int t = 0; t < 12; ++t)
            #pragma unroll
            for (int r = 0; r < 4; ++r)
                H0[(size_t)(row0 + quad*4 + r)*HH + t*16 + m] = fmaxf(acc[t][r], 0.f);
    } else {
        const float* dis = ws + OFF_DIS;
        __hip_bfloat16* Z = (__hip_bfloat16*)(ws + OFF_ZB);
        float sc[4];
        #pragma unroll
        for (int r = 0; r < 4; ++r) sc[r] = dis[row0 + quad*4 + r];
        #pragma unroll
        for (int t = 0; t < 12; ++t)
            #pragma unroll
            for (int r = 0; r < 4; ++r)
                Z[(size_t)(row0 + quad*4 + r)*HH + t*16 + m] =
                    __float2bfloat16(acc[t][r] * sc[r]);
    }
}

// H0 = relu( dis_i * sum_{j in N(i)} Z'[j] + bias[layer] ). 1 block (192thr)/row.
__global__ void spmm(const void* __restrict__ bias, int layer, float* ws) {
    int row = blockIdx.x, tid = threadIdx.x;
    const int isf = ((const int*)ws)[OFF_FLAG];
    const float* dis = ws + OFF_DIS;
    int c = ((const int*)(ws + OFF_CNT))[row];
    const unsigned short* cl = (const unsigned short*)(ws + OFF_COLS) + (size_t)row*MAXC;
    const __hip_bfloat16* Z = (const __hip_bfloat16*)(ws + OFF_ZB);
    int base = (row >> 10) << 10;
    float acc = 0.f;
    int k = 0;
    for (; k + 4 <= c; k += 4) {
        int j0 = base + cl[k],   j1 = base + cl[k+1];
        int j2 = base + cl[k+2], j3 = base + cl[k+3];
        acc += bf(Z[(size_t)j0*HH + tid]) + bf(Z[(size_t)j1*HH + tid])
             + bf(Z[(size_t)j2*HH + tid]) + bf(Z[(size_t)j3*HH + tid]);
    }
    for (; k < c; ++k) acc += bf(Z[(size_t)(base + cl[k])*HH + tid]);
    float o = dis[row]*acc + ldin(bias, (size_t)layer*HH + tid, isf);
    ws[OFF_H0 + (size_t)row*HH + tid] = fmaxf(o, 0.f);
}

// Pool partial sums: grid 128 (16 batches x 8 segments), atomicAdd into g (pre-zeroed).
__global__ void pool(const float* __restrict__ h, float* __restrict__ g) {
    int b = blockIdx.x >> 3, seg = blockIdx.x & 7, tid = threadIdx.x;
    float acc = 0.f;
    int n0 = b*NN + seg*(NN/8);
    for (int n = 0; n < NN/8; ++n)
        acc += h[(size_t)(n0 + n)*HH + tid];
    atomicAdd(&g[b*HH + tid], acc);
}

// BN -> relu(linear) -> BN -> classifier -> log_softmax. One block, 256 thr.
// g holds SUMS over N (scale by 1/NN here).
__global__ void tail(const float* __restrict__ g,
                     const void* __restrict__ fc_g,  const void* __restrict__ fc_b,
                     const void* __restrict__ lin_W, const void* __restrict__ lin_b,
                     const void* __restrict__ hid_g, const void* __restrict__ hid_b,
                     const void* __restrict__ cls_W, const void* __restrict__ cls_b,
                     void* __restrict__ out, const float* ws) {
    __shared__ float g1[BB][HH];
    __shared__ float g2[BB][HH];
    __shared__ float logits[BB][10];
    __shared__ float lse[BB];
    int tid = threadIdx.x;
    const int isf = ((const int*)ws)[OFF_FLAG];
    if (tid < HH) {
        float s = 0.f, sq = 0.f;
        for (int b = 0; b < BB; ++b) {
            float v = g[b*HH + tid] * (1.f/NN);
            s += v; sq += v*v;
        }
        float m = s*(1.f/BB), var = sq*(1.f/BB) - m*m;
        float a = ldin(fc_g, tid, isf) * rsqrtf(var + EPSV);
        float c = ldin(fc_b, tid, isf) - m*a;
        for (int b = 0; b < BB; ++b) g1[b][tid] = g[b*HH + tid]*(1.f/NN)*a + c;
    }
    __syncthreads();
    if (tid < HH) {
        if (isf) {
            const float* Wp = (const float*)lin_W;
            for (int b = 0; b < BB; ++b) {
                float acc = ldin(lin_b, tid, isf);
                for (int h = 0; h < HH; ++h) acc += g1[b][h] * Wp[h*HH + tid];
                g2[b][tid] = fmaxf(acc, 0.f);
            }
        } else {
            const __hip_bfloat16* Wp = (const __hip_bfloat16*)lin_W;
            for (int b = 0; b < BB; ++b) {
                float acc = ldin(lin_b, tid, isf);
                for (int h = 0; h < HH; ++h) acc += g1[b][h] * bf(Wp[h*HH + tid]);
                g2[b][tid] = fmaxf(acc, 0.f);
            }
        }
    }
    __syncthreads();
    if (tid < HH) {
        float s = 0.f, sq = 0.f;
        for (int b = 0; b < BB; ++b) { float v = g2[b][tid]; s += v; sq += v*v; }
        float m = s*(1.f/BB), var = sq*(1.f/BB) - m*m;
        float a = ldin(hid_g, tid, isf) * rsqrtf(var + EPSV);
        float c = ldin(hid_b, tid, isf) - m*a;
        for (int b = 0; b < BB; ++b) g2[b][tid] = g2[b][tid]*a + c;
    }
    __syncthreads();
    if (tid < BB*10) {
        int b = tid/10, k = tid%10;
        float acc = ldin(cls_b, k, isf);
        if (isf) {
            const float* Wp = (const float*)cls_W;
            for (int h = 0; h < HH; ++h) acc += g2[b][h] * Wp[h*10 + k];
        } else {
            const __hip_bfloat16* Wp = (const __hip_bfloat16*)cls_W;
            for (int h = 0; h < HH; ++h) acc += g2[b][h] * bf(Wp[h*10 + k]);
        }
        logits[b][k] = acc;
    }
    __syncthreads();
    if (tid < BB) {
        float m = -1e30f;
        for (int k = 0; k < 10; ++k) m = fmaxf(m, logits[tid][k]);
        float s = 0.f;
        for (int k = 0; k < 10; ++k) s += expf(logits[tid][k] - m);
        lse[tid] = m + logf(s);
    }
    __syncthreads();
    if (tid < BB*10) {
        int b = tid/10;
        float v = logits[b][tid%10] - lse[b];
        if (isf) ((float*)out)[tid] = v;
        else     ((__hip_bfloat16*)out)[tid] = __float2bfloat16(v);
    }
}

extern "C" void kernel_launch(void* const* d_in, const int* in_sizes, int n_in,
                              void* d_out, int out_size, void* d_ws, size_t ws_size,
                              hipStream_t stream) {
    const void* x       = d_in[0];
    const void* adj     = d_in[1];
    const void* bnf_g   = d_in[2];
    const void* bnf_b   = d_in[3];
    const void* W_feat  = d_in[4];
    const void* bnc_g   = d_in[5];
    const void* bnc_b   = d_in[6];
    const void* convs_W = d_in[7];
    const void* convs_b = d_in[8];
    const void* fc_g    = d_in[9];
    const void* fc_b    = d_in[10];
    const void* lin_W   = d_in[11];
    const void* lin_b   = d_in[12];
    const void* hid_g   = d_in[13];
    const void* hid_b   = d_in[14];
    const void* cls_W   = d_in[15];
    const void* cls_b   = d_in[16];

    float* ws = (float*)d_ws;
    float* H0 = ws + OFF_H0;
    const __hip_bfloat16* Xn = (const __hip_bfloat16*)(ws + OFF_XN);
    const __hip_bfloat16* Hb = (const __hip_bfloat16*)(ws + OFF_HB);
    const __hip_bfloat16* WT = (const __hip_bfloat16*)(ws + OFF_WT);

    detect_and_zero<<<1, 256, 0, stream>>>((const unsigned int*)adj, ws);
    build_graph<<<NROWS, 256, 0, stream>>>(adj, ws);
    prep_wt<<<4*HH, HH, 0, stream>>>(W_feat, convs_W, ws);
    stats_x<<<256, FF, 0, stream>>>(x, ws);
    bn_cast_x<<<NROWS*FF/256, 256, 0, stream>>>(x, bnf_g, bnf_b, ws);
    gemm_mfma<FF, 0><<<NROWS/64, 256, 0, stream>>>(Xn, WT + WT_FEAT, ws);
    for (int l = 0; l < 3; ++l) {
        stats_h<<<64, HH, 0, stream>>>(H0, ws, 1 + l);
        bn_cast_h<<<NROWS/4, HH, 0, stream>>>(H0, bnc_g, bnc_b, l, ws);
        gemm_mfma<HH, 1><<<NROWS/64, 256, 0, stream>>>(
            Hb, WT + WT_CONV + (size_t)l*HH*HH, ws);
        spmm<<<NROWS, HH, 0, stream>>>(convs_b, l, ws);
    }
    pool<<<128, HH, 0, stream>>>(H0, ws + OFF_G);
    tail<<<1, 256, 0, stream>>>(ws + OFF_G, fc_g, fc_b, lin_W, lin_b,
                                hid_g, hid_b, cls_W, cls_b, d_out, ws);
}

// Round 4
// 414.310 us; speedup vs baseline: 2.0325x; 1.0753x over previous
//
#include <hip/hip_runtime.h>
#include <hip/hip_bf16.h>

#define BB 16
#define NN 1024
#define FF 128
#define HH 192
#define NROWS (BB*NN)
#define MAXC 128
#define EPSV 1e-5f

// workspace layout, in float (4B) units (~17 MB total)
constexpr size_t OFF_H0  = 0;                                   // [NROWS*HH] bf16 (h, post-relu)
constexpr size_t OFF_ZB  = OFF_H0 + (size_t)NROWS*HH/2;         // [NROWS*HH] bf16 (Z' = dis_j*(hW'+bias))
constexpr size_t OFF_WPF = OFF_ZB + (size_t)NROWS*HH/2;         // [HH*FF] bf16  feat W'T (a-scaled)
constexpr size_t OFF_WPC = OFF_WPF + (size_t)HH*FF/2;           // [HH*HH] bf16  conv W'T (reused per layer)
constexpr size_t OFF_BF  = OFF_WPC + (size_t)HH*HH/2;           // [HH] f32 feat bias (c@W)
constexpr size_t OFF_BC  = OFF_BF + HH;                         // [HH] f32 conv bias (c@W)
constexpr size_t OFF_DIS = OFF_BC + HH;                         // [NROWS] f32
constexpr size_t OFF_G   = OFF_DIS + NROWS;                     // [BB*HH] f32 pool sums (atomics)
constexpr size_t OFF_ST  = OFF_G + BB*HH;                       // 4 stages * 2 * 256 f32
constexpr size_t OFF_FLAG= OFF_ST + 4*2*256;                    // 1 int (1 => inputs f32)
constexpr size_t OFF_CNT = OFF_FLAG + 1;                        // [NROWS] int32
constexpr size_t OFF_COLS= OFF_CNT + NROWS;                     // [NROWS*MAXC] u16

typedef __attribute__((ext_vector_type(8))) short short8;   // 8 bf16 in 4 VGPRs
typedef __attribute__((ext_vector_type(4))) float f32x4;

static __device__ __forceinline__ float bf(const __hip_bfloat16 v) {
    return __bfloat162float(v);
}
static __device__ __forceinline__ float ldin(const void* p, size_t i, int isf) {
    return isf ? ((const float*)p)[i]
               : __bfloat162float(((const __hip_bfloat16*)p)[i]);
}

// Detect input dtype from adj bit patterns; zero BN-stat accumulators + pool sums.
__global__ void detect_and_zero(const unsigned int* __restrict__ adjw, float* ws) {
    __shared__ int evid;
    int tid = threadIdx.x;
    if (tid == 0) evid = 0;
    __syncthreads();
    int local = 0;
    for (int k = tid; k < 16384; k += 256) {
        unsigned int w = adjw[k];
        if ((w & 0xFFFFu) == 0x3F80u) local++;   // bf16-packed even-index 1.0
    }
    if (local) atomicAdd(&evid, local);
    for (int k = tid; k < 4*2*256; k += 256) ws[OFF_ST + k] = 0.f;
    for (int k = tid; k < BB*HH; k += 256) ws[OFF_G + k] = 0.f;
    __syncthreads();
    if (tid == 0) ((int*)ws)[OFF_FLAG] = (evid == 0) ? 1 : 0;
}

// One block (256 thr) per adjacency row: neighbor list + dis = rsqrt(deg).
__global__ void build_graph(const void* __restrict__ adj, float* ws) {
    int row = blockIdx.x;
    int i   = row & (NN - 1);
    int tid = threadIdx.x;
    const int isf = ((const int*)ws)[OFF_FLAG];
    __shared__ int cnt_s;
    __shared__ unsigned short colbuf[MAXC];
    if (tid == 0) cnt_s = 0;
    __syncthreads();
    if (isf) {
        const float* ar = (const float*)adj + (size_t)row * NN;
        for (int j = tid; j < NN; j += 256) {
            if (ar[j] != 0.f || j == i) {
                int p = atomicAdd(&cnt_s, 1);
                if (p < MAXC) colbuf[p] = (unsigned short)j;
            }
        }
    } else {
        const __hip_bfloat16* ar = (const __hip_bfloat16*)adj + (size_t)row * NN;
        for (int j = tid; j < NN; j += 256) {
            if (bf(ar[j]) != 0.f || j == i) {
                int p = atomicAdd(&cnt_s, 1);
                if (p < MAXC) colbuf[p] = (unsigned short)j;
            }
        }
    }
    __syncthreads();
    int c = cnt_s; if (c > MAXC) c = MAXC;
    if (tid == 0) {
        ((int*)(ws + OFF_CNT))[row] = c;
        ws[OFF_DIS + row] = rsqrtf((float)cnt_s);   // deg >= 1 (self loop)
    }
    unsigned short* cols = (unsigned short*)(ws + OFF_COLS);
    for (int k = tid; k < c; k += 256) cols[(size_t)row*MAXC + k] = colbuf[k];
}

// Per-feature sum/sumsq of x. 256 blocks x 128 thr (thread = feature).
__global__ void stats_x(const void* __restrict__ x, float* ws) {
    int tid = threadIdx.x;
    int r0  = blockIdx.x * (NROWS/256);
    const int isf = ((const int*)ws)[OFF_FLAG];
    float s = 0.f, sq = 0.f;
    if (isf) {
        const float* xp = (const float*)x;
        for (int r = 0; r < NROWS/256; ++r) {
            float v = xp[(size_t)(r0 + r)*FF + tid];
            s += v; sq += v*v;
        }
    } else {
        const __hip_bfloat16* xp = (const __hip_bfloat16*)x;
        for (int r = 0; r < NROWS/256; ++r) {
            float v = bf(xp[(size_t)(r0 + r)*FF + tid]);
            s += v; sq += v*v;
        }
    }
    float* st = ws + OFF_ST;
    atomicAdd(&st[tid], s);
    atomicAdd(&st[256 + tid], sq);
}

// BN-fold for feat layer: W'T[n][k] = a_k * W[k][n] (bf16), biasF[n] = sum_k c_k W[k][n].
// grid HH blocks (n), FF threads (k).
__global__ void prep_feat(const void* __restrict__ W_feat,
                          const void* __restrict__ gg, const void* __restrict__ bb,
                          float* ws) {
    const int isf = ((const int*)ws)[OFF_FLAG];
    int n = blockIdx.x, k = threadIdx.x;
    const float* st = ws + OFF_ST;
    float m   = st[k] * (1.f/NROWS);
    float var = st[256+k] * (1.f/NROWS) - m*m;
    float a   = ldin(gg, k, isf) * rsqrtf(var + EPSV);
    float c   = ldin(bb, k, isf) - m*a;
    float wv  = ldin(W_feat, (size_t)k*HH + n, isf);
    ((__hip_bfloat16*)(ws + OFF_WPF))[(size_t)n*FF + k] = __float2bfloat16(a*wv);
    __shared__ float red[FF];
    red[k] = c*wv;
    __syncthreads();
    for (int s = FF/2; s > 0; s >>= 1) {
        if (k < s) red[k] += red[k + s];
        __syncthreads();
    }
    if (k == 0) ws[OFF_BF + n] = red[0];
}

// BN-fold for conv layer l. grid HH blocks (n), HH threads (k).
__global__ void prep_conv(const void* __restrict__ convs_W,
                          const void* __restrict__ gg, const void* __restrict__ bb,
                          int layer, float* ws) {
    const int isf = ((const int*)ws)[OFF_FLAG];
    int n = blockIdx.x, k = threadIdx.x;
    const float* st = ws + OFF_ST + (size_t)(1 + layer)*512;
    float m   = st[k] * (1.f/NROWS);
    float var = st[256+k] * (1.f/NROWS) - m*m;
    float a   = ldin(gg, (size_t)layer*HH + k, isf) * rsqrtf(var + EPSV);
    float c   = ldin(bb, (size_t)layer*HH + k, isf) - m*a;
    float wv  = ldin(convs_W, (size_t)layer*HH*HH + (size_t)k*HH + n, isf);
    ((__hip_bfloat16*)(ws + OFF_WPC))[(size_t)n*HH + k] = __float2bfloat16(a*wv);
    __shared__ float red[HH];
    red[k] = c*wv;
    __syncthreads();
    if (k < 96) red[k] += red[k + 96];
    __syncthreads();
    for (int s = 48; s >= 3; s >>= 1) {
        if (k < s) red[k] += red[k + s];
        __syncthreads();
    }
    if (k == 0) ws[OFF_BC + n] = red[0] + red[1] + red[2];
}

// Per-channel sum/sumsq of bf16 h. 128 blocks x 192 thr.
__global__ void stats_h(float* ws, int stage) {
    const __hip_bfloat16* h = (const __hip_bfloat16*)(ws + OFF_H0);
    int tid = threadIdx.x;
    int r0  = blockIdx.x * (NROWS/128);
    float s = 0.f, sq = 0.f;
    for (int r = 0; r < NROWS/128; ++r) {
        float v = bf(h[(size_t)(r0 + r)*HH + tid]);
        s += v; sq += v*v;
    }
    float* st = ws + OFF_ST + (size_t)stage*512;
    atomicAdd(&st[tid], s);
    atomicAdd(&st[256 + tid], sq);
}

// C = A[M x K] @ W'T[N x K]^T + bias via MFMA 16x16x32 bf16.
// Block 256thr = 4 waves, wave owns 16 rows x 192 cols. grid = NROWS/64.
// MODE 0 (feat): A = x (isf-dependent dtype), out H0 = bf16(relu(C)).
// MODE 1 (conv): A = H0 bf16, out Z' = bf16(dis[row] * C).
template<int K, int MODE>
__global__ __launch_bounds__(256) void gemm_mfma(const void* __restrict__ A,
                                                 const __hip_bfloat16* __restrict__ BT,
                                                 const float* __restrict__ bias,
                                                 float* __restrict__ ws) {
    const int isf = ((const int*)ws)[OFF_FLAG];
    int lane = threadIdx.x & 63, w = threadIdx.x >> 6;
    int row0 = blockIdx.x*64 + w*16;
    int m    = lane & 15, quad = lane >> 4;
    f32x4 acc[12];
    #pragma unroll
    for (int t = 0; t < 12; ++t) acc[t] = f32x4{0.f,0.f,0.f,0.f};
    float bv[12];
    #pragma unroll
    for (int t = 0; t < 12; ++t) bv[t] = bias[t*16 + m];
    #pragma unroll
    for (int kb = 0; kb < K/32; ++kb) {
        short8 a;
        if (MODE == 0 && isf) {
            const float* Ar = (const float*)A + (size_t)(row0+m)*K + kb*32 + quad*8;
            f32x4 v0 = *(const f32x4*)Ar;
            f32x4 v1 = *(const f32x4*)(Ar + 4);
            union { short8 s8; __hip_bfloat16 h[8]; } u;
            #pragma unroll
            for (int e = 0; e < 4; ++e) {
                u.h[e]   = __float2bfloat16(v0[e]);
                u.h[e+4] = __float2bfloat16(v1[e]);
            }
            a = u.s8;
        } else {
            a = *(const short8*)((const __hip_bfloat16*)A +
                                 (size_t)(row0+m)*K + kb*32 + quad*8);
        }
        #pragma unroll
        for (int t = 0; t < 12; ++t) {
            short8 b = *(const short8*)(BT + (size_t)(t*16+m)*K + kb*32 + quad*8);
            acc[t] = __builtin_amdgcn_mfma_f32_16x16x32_bf16(a, b, acc[t], 0, 0, 0);
        }
    }
    if (MODE == 0) {
        __hip_bfloat16* H0 = (__hip_bfloat16*)(ws + OFF_H0);
        #pragma unroll
        for (int t = 0; t < 12; ++t)
            #pragma unroll
            for (int r = 0; r < 4; ++r)
                H0[(size_t)(row0 + quad*4 + r)*HH + t*16 + m] =
                    __float2bfloat16(fmaxf(acc[t][r] + bv[t], 0.f));
    } else {
        const float* dis = ws + OFF_DIS;
        __hip_bfloat16* Z = (__hip_bfloat16*)(ws + OFF_ZB);
        float sc[4];
        #pragma unroll
        for (int r = 0; r < 4; ++r) sc[r] = dis[row0 + quad*4 + r];
        #pragma unroll
        for (int t = 0; t < 12; ++t)
            #pragma unroll
            for (int r = 0; r < 4; ++r)
                Z[(size_t)(row0 + quad*4 + r)*HH + t*16 + m] =
                    __float2bfloat16((acc[t][r] + bv[t]) * sc[r]);
    }
}

// H0 = bf16(relu( dis_i * sum_{j in N(i)} Z'[j] + conv_bias[layer] )). 1 block/row.
__global__ void spmm(const void* __restrict__ bias, int layer, float* ws) {
    int row = blockIdx.x, tid = threadIdx.x;
    const int isf = ((const int*)ws)[OFF_FLAG];
    const float* dis = ws + OFF_DIS;
    int c = ((const int*)(ws + OFF_CNT))[row];
    const unsigned short* cl = (const unsigned short*)(ws + OFF_COLS) + (size_t)row*MAXC;
    const __hip_bfloat16* Z = (const __hip_bfloat16*)(ws + OFF_ZB);
    int base = (row >> 10) << 10;
    float acc = 0.f;
    int k = 0;
    for (; k + 4 <= c; k += 4) {
        int j0 = base + cl[k],   j1 = base + cl[k+1];
        int j2 = base + cl[k+2], j3 = base + cl[k+3];
        acc += bf(Z[(size_t)j0*HH + tid]) + bf(Z[(size_t)j1*HH + tid])
             + bf(Z[(size_t)j2*HH + tid]) + bf(Z[(size_t)j3*HH + tid]);
    }
    for (; k < c; ++k) acc += bf(Z[(size_t)(base + cl[k])*HH + tid]);
    float o = dis[row]*acc + ldin(bias, (size_t)layer*HH + tid, isf);
    ((__hip_bfloat16*)(ws + OFF_H0))[(size_t)row*HH + tid] =
        __float2bfloat16(fmaxf(o, 0.f));
}

// Pool partial sums: grid 128 (16 batches x 8 segments), atomicAdd into g (pre-zeroed).
__global__ void pool(float* ws) {
    const __hip_bfloat16* h = (const __hip_bfloat16*)(ws + OFF_H0);
    float* g = ws + OFF_G;
    int b = blockIdx.x >> 3, seg = blockIdx.x & 7, tid = threadIdx.x;
    float acc = 0.f;
    int n0 = b*NN + seg*(NN/8);
    for (int n = 0; n < NN/8; ++n)
        acc += bf(h[(size_t)(n0 + n)*HH + tid]);
    atomicAdd(&g[b*HH + tid], acc);
}

// BN -> relu(linear) -> BN -> classifier -> log_softmax. One block, 768 thr.
// lin_W staged in LDS; linear phase: thread = (b-group of 4, col n).
__global__ __launch_bounds__(768) void tail(
                     const void* __restrict__ fc_g,  const void* __restrict__ fc_b,
                     const void* __restrict__ lin_W, const void* __restrict__ lin_b,
                     const void* __restrict__ hid_g, const void* __restrict__ hid_b,
                     const void* __restrict__ cls_W, const void* __restrict__ cls_b,
                     void* __restrict__ out, const float* ws) {
    __shared__ float g1[BB][HH];
    __shared__ float g2[BB][HH];
    __shared__ __hip_bfloat16 Wl[HH*HH];
    __shared__ float logits[BB][10];
    __shared__ float lse[BB];
    int tid = threadIdx.x;
    const int isf = ((const int*)ws)[OFF_FLAG];
    const float* g = ws + OFF_G;   // sums over N; scale by 1/NN
    // stage lin_W -> LDS (bf16)
    if (isf) {
        const float* Wp = (const float*)lin_W;
        for (int i = tid; i < HH*HH; i += 768) Wl[i] = __float2bfloat16(Wp[i]);
    } else {
        const __hip_bfloat16* Wp = (const __hip_bfloat16*)lin_W;
        for (int i = tid; i < HH*HH; i += 768) Wl[i] = Wp[i];
    }
    // BN of pooled g
    if (tid < HH) {
        float s = 0.f, sq = 0.f;
        for (int b = 0; b < BB; ++b) {
            float v = g[b*HH + tid] * (1.f/NN);
            s += v; sq += v*v;
        }
        float m = s*(1.f/BB), var = sq*(1.f/BB) - m*m;
        float a = ldin(fc_g, tid, isf) * rsqrtf(var + EPSV);
        float c = ldin(fc_b, tid, isf) - m*a;
        for (int b = 0; b < BB; ++b) g1[b][tid] = g[b*HH + tid]*(1.f/NN)*a + c;
    }
    __syncthreads();
    // linear: 768 = 4 b-groups x 192 cols; each thread 4 outputs (same col)
    {
        int n = tid % HH, bg = tid / HH;           // bg in 0..3
        float lb = ldin(lin_b, n, isf);
        float a0 = lb, a1 = lb, a2 = lb, a3 = lb;
        int b0 = bg*4;
        for (int k = 0; k < HH; ++k) {
            float wv = bf(Wl[k*HH + n]);
            a0 += g1[b0+0][k]*wv;
            a1 += g1[b0+1][k]*wv;
            a2 += g1[b0+2][k]*wv;
            a3 += g1[b0+3][k]*wv;
        }
        g2[b0+0][n] = fmaxf(a0, 0.f);
        g2[b0+1][n] = fmaxf(a1, 0.f);
        g2[b0+2][n] = fmaxf(a2, 0.f);
        g2[b0+3][n] = fmaxf(a3, 0.f);
    }
    __syncthreads();
    // BN of g2
    if (tid < HH) {
        float s = 0.f, sq = 0.f;
        for (int b = 0; b < BB; ++b) { float v = g2[b][tid]; s += v; sq += v*v; }
        float m = s*(1.f/BB), var = sq*(1.f/BB) - m*m;
        float a = ldin(hid_g, tid, isf) * rsqrtf(var + EPSV);
        float c = ldin(hid_b, tid, isf) - m*a;
        for (int b = 0; b < BB; ++b) g2[b][tid] = g2[b][tid]*a + c;
    }
    __syncthreads();
    // classifier
    if (tid < BB*10) {
        int b = tid/10, k = tid%10;
        float acc = ldin(cls_b, k, isf);
        for (int h = 0; h < HH; ++h) acc += g2[b][h] * ldin(cls_W, (size_t)h*10 + k, isf);
        logits[b][k] = acc;
    }
    __syncthreads();
    if (tid < BB) {
        float m = -1e30f;
        for (int k = 0; k < 10; ++k) m = fmaxf(m, logits[tid][k]);
        float s = 0.f;
        for (int k = 0; k < 10; ++k) s += expf(logits[tid][k] - m);
        lse[tid] = m + logf(s);
    }
    __syncthreads();
    if (tid < BB*10) {
        int b = tid/10;
        float v = logits[b][tid%10] - lse[b];
        if (isf) ((float*)out)[tid] = v;
        else     ((__hip_bfloat16*)out)[tid] = __float2bfloat16(v);
    }
}

extern "C" void kernel_launch(void* const* d_in, const int* in_sizes, int n_in,
                              void* d_out, int out_size, void* d_ws, size_t ws_size,
                              hipStream_t stream) {
    const void* x       = d_in[0];
    const void* adj     = d_in[1];
    const void* bnf_g   = d_in[2];
    const void* bnf_b   = d_in[3];
    const void* W_feat  = d_in[4];
    const void* bnc_g   = d_in[5];
    const void* bnc_b   = d_in[6];
    const void* convs_W = d_in[7];
    const void* convs_b = d_in[8];
    const void* fc_g    = d_in[9];
    const void* fc_b    = d_in[10];
    const void* lin_W   = d_in[11];
    const void* lin_b   = d_in[12];
    const void* hid_g   = d_in[13];
    const void* hid_b   = d_in[14];
    const void* cls_W   = d_in[15];
    const void* cls_b   = d_in[16];

    float* ws = (float*)d_ws;
    const __hip_bfloat16* WPF = (const __hip_bfloat16*)(ws + OFF_WPF);
    const __hip_bfloat16* WPC = (const __hip_bfloat16*)(ws + OFF_WPC);

    detect_and_zero<<<1, 256, 0, stream>>>((const unsigned int*)adj, ws);
    build_graph<<<NROWS, 256, 0, stream>>>(adj, ws);
    stats_x<<<256, FF, 0, stream>>>(x, ws);
    prep_feat<<<HH, FF, 0, stream>>>(W_feat, bnf_g, bnf_b, ws);
    gemm_mfma<FF, 0><<<NROWS/64, 256, 0, stream>>>(x, WPF, ws + OFF_BF, ws);
    for (int l = 0; l < 3; ++l) {
        stats_h<<<128, HH, 0, stream>>>(ws, 1 + l);
        prep_conv<<<HH, HH, 0, stream>>>(convs_W, bnc_g, bnc_b, l, ws);
        gemm_mfma<HH, 1><<<NROWS/64, 256, 0, stream>>>(
            (const void*)(ws + OFF_H0), WPC, ws + OFF_BC, ws);
        spmm<<<NROWS, HH, 0, stream>>>(convs_b, l, ws);
    }
    pool<<<128, HH, 0, stream>>>(ws);
    tail<<<1, 768, 0, stream>>>(fc_g, fc_b, lin_W, lin_b,
                                hid_g, hid_b, cls_W, cls_b, d_out, ws);
}

// Round 6
// 387.096 us; speedup vs baseline: 2.1754x; 1.0703x over previous
//
#include <hip/hip_runtime.h>
#include <hip/hip_bf16.h>

#define BB 16
#define NN 1024
#define FF 128
#define HH 192
#define NROWS (BB*NN)
#define MAXC 128
#define EPSV 1e-5f

// workspace layout, in float (4B) units (~17 MB total)
constexpr size_t OFF_H0  = 0;                                   // [NROWS*HH] bf16 (h, post-relu)
constexpr size_t OFF_ZB  = OFF_H0 + (size_t)NROWS*HH/2;         // [NROWS*HH] bf16 (Z' = dis_j*(hW'+bias))
constexpr size_t OFF_WPF = OFF_ZB + (size_t)NROWS*HH/2;         // [HH*FF] bf16  feat W'T
constexpr size_t OFF_WPC = OFF_WPF + (size_t)HH*FF/2;           // [HH*HH] bf16  conv W'T (per layer)
constexpr size_t OFF_BF  = OFF_WPC + (size_t)HH*HH/2;           // [HH] f32 feat bias (c@W)
constexpr size_t OFF_BC  = OFF_BF + HH;                         // [HH] f32 conv bias (c@W)
constexpr size_t OFF_DIS = OFF_BC + HH;                         // [NROWS] f32
constexpr size_t OFF_G   = OFF_DIS + NROWS;                     // [BB*HH] f32 pool sums (atomics)
// stats: stage0 (x): 512 single-bucket; stages 1..3 (h): 8 buckets x 512 each
constexpr size_t OFF_ST  = OFF_G + BB*HH;
constexpr size_t ST_SIZE = 512 + 3*8*512;                       // 12800 floats
constexpr size_t OFF_FLAG= OFF_ST + ST_SIZE;                    // 1 int (1 => inputs f32)
constexpr size_t OFF_CNT = OFF_FLAG + 1;                        // [NROWS] int32
constexpr size_t OFF_COLS= OFF_CNT + NROWS;                     // [NROWS*MAXC] u16

typedef __attribute__((ext_vector_type(8))) short short8;   // 8 bf16 in 4 VGPRs
typedef __attribute__((ext_vector_type(4))) float f32x4;
typedef __attribute__((ext_vector_type(4))) unsigned int u32x4;
typedef __attribute__((ext_vector_type(2))) unsigned int u32x2;

static __device__ __forceinline__ float bf(const __hip_bfloat16 v) {
    return __bfloat162float(v);
}
static __device__ __forceinline__ float ldin(const void* p, size_t i, int isf) {
    return isf ? ((const float*)p)[i]
               : __bfloat162float(((const __hip_bfloat16*)p)[i]);
}
static __host__ __device__ __forceinline__ float* stage_h(float* ws, int s /*0..2*/) {
    return ws + OFF_ST + 512 + (size_t)s*8*512;
}

// Detect input dtype from adj bit patterns; zero stat accumulators + pool sums.
__global__ void detect_and_zero(const unsigned int* __restrict__ adjw, float* ws) {
    __shared__ int evid;
    int tid = threadIdx.x;
    if (tid == 0) evid = 0;
    __syncthreads();
    int local = 0;
    for (int k = tid; k < 16384; k += 256) {
        unsigned int w = adjw[k];
        if ((w & 0xFFFFu) == 0x3F80u) local++;   // bf16-packed even-index 1.0
    }
    if (local) atomicAdd(&evid, local);
    for (size_t k = tid; k < ST_SIZE; k += 256) ws[OFF_ST + k] = 0.f;
    for (int k = tid; k < BB*HH; k += 256) ws[OFF_G + k] = 0.f;
    __syncthreads();
    if (tid == 0) ((int*)ws)[OFF_FLAG] = (evid == 0) ? 1 : 0;
}

// Role-split kernel: blocks [0,NROWS) build graph rows; blocks [NROWS, NROWS+256)
// compute per-feature stats of x (stage 0).
__global__ __launch_bounds__(256) void phase1(const void* __restrict__ adj,
                                              const void* __restrict__ x, float* ws) {
    const int isf = ((const int*)ws)[OFF_FLAG];
    int tid = threadIdx.x;
    if (blockIdx.x < NROWS) {
        int row = blockIdx.x;
        int i   = row & (NN - 1);
        __shared__ int cnt_s;
        __shared__ unsigned short colbuf[MAXC];
        if (tid == 0) cnt_s = 0;
        __syncthreads();
        int j0 = tid*4;
        unsigned int bits[4];
        if (isf) {
            u32x4 v = *(const u32x4*)((const unsigned int*)adj + (size_t)row*NN + j0);
            bits[0]=v[0]; bits[1]=v[1]; bits[2]=v[2]; bits[3]=v[3];
        } else {
            u32x2 v = *(const u32x2*)((const unsigned short*)adj + (size_t)row*NN + j0);
            bits[0]=(v[0]&0xFFFFu); bits[1]=(v[0]>>16); bits[2]=(v[1]&0xFFFFu); bits[3]=(v[1]>>16);
        }
        #pragma unroll
        for (int e = 0; e < 4; ++e) {
            int j = j0 + e;
            if ((bits[e] << 1) != 0u || j == i) {   // value != +-0  (or self loop)
                int p = atomicAdd(&cnt_s, 1);
                if (p < MAXC) colbuf[p] = (unsigned short)j;
            }
        }
        __syncthreads();
        int c = cnt_s; if (c > MAXC) c = MAXC;
        if (tid == 0) {
            ((int*)(ws + OFF_CNT))[row] = c;
            ws[OFF_DIS + row] = rsqrtf((float)cnt_s);   // deg >= 1 (self loop)
        }
        unsigned short* cols = (unsigned short*)(ws + OFF_COLS);
        for (int k = tid; k < c; k += 256) cols[(size_t)row*MAXC + k] = colbuf[k];
    } else {
        int b2 = blockIdx.x - NROWS;          // 0..255
        int f = tid & (FF-1), half = tid >> 7;
        int r0 = b2*64 + half*32;
        float s = 0.f, sq = 0.f;
        for (int r = 0; r < 32; ++r) {
            float v = ldin(x, (size_t)(r0 + r)*FF + f, isf);
            s += v; sq += v*v;
        }
        atomicAdd(&ws[OFF_ST + f], s);
        atomicAdd(&ws[OFF_ST + 256 + f], sq);
    }
}

// BN-fold for feat layer: W'T[n][k] = a_k * W[k][n] (bf16), biasF[n] = sum_k c_k W[k][n].
__global__ void prep_feat(const void* __restrict__ W_feat,
                          const void* __restrict__ gg, const void* __restrict__ bb,
                          float* ws) {
    const int isf = ((const int*)ws)[OFF_FLAG];
    int n = blockIdx.x, k = threadIdx.x;
    const float* st = ws + OFF_ST;
    float m   = st[k] * (1.f/NROWS);
    float var = st[256+k] * (1.f/NROWS) - m*m;
    float a   = ldin(gg, k, isf) * rsqrtf(var + EPSV);
    float c   = ldin(bb, k, isf) - m*a;
    float wv  = ldin(W_feat, (size_t)k*HH + n, isf);
    ((__hip_bfloat16*)(ws + OFF_WPF))[(size_t)n*FF + k] = __float2bfloat16(a*wv);
    __shared__ float red[FF];
    red[k] = c*wv;
    __syncthreads();
    for (int s = FF/2; s > 0; s >>= 1) {
        if (k < s) red[k] += red[k + s];
        __syncthreads();
    }
    if (k == 0) ws[OFF_BF + n] = red[0];
}

// BN-fold for conv layer l (reads 8-bucket stats of stage l).
__global__ void prep_conv(const void* __restrict__ convs_W,
                          const void* __restrict__ gg, const void* __restrict__ bb,
                          int layer, float* ws) {
    const int isf = ((const int*)ws)[OFF_FLAG];
    int n = blockIdx.x, k = threadIdx.x;
    const float* st = stage_h(ws, layer);
    float s = 0.f, sq = 0.f;
    #pragma unroll
    for (int bkt = 0; bkt < 8; ++bkt) {
        s  += st[bkt*512 + k];
        sq += st[bkt*512 + 256 + k];
    }
    float m   = s * (1.f/NROWS);
    float var = sq * (1.f/NROWS) - m*m;
    float a   = ldin(gg, (size_t)layer*HH + k, isf) * rsqrtf(var + EPSV);
    float c   = ldin(bb, (size_t)layer*HH + k, isf) - m*a;
    float wv  = ldin(convs_W, (size_t)layer*HH*HH + (size_t)k*HH + n, isf);
    ((__hip_bfloat16*)(ws + OFF_WPC))[(size_t)n*HH + k] = __float2bfloat16(a*wv);
    __shared__ float red[HH];
    red[k] = c*wv;
    __syncthreads();
    if (k < 96) red[k] += red[k + 96];
    __syncthreads();
    for (int s2 = 48; s2 >= 3; s2 >>= 1) {
        if (k < s2) red[k] += red[k + s2];
        __syncthreads();
    }
    if (k == 0) ws[OFF_BC + n] = red[0] + red[1] + red[2];
}

// C = A[M x K] @ W'T[N x K]^T + bias via MFMA 16x16x32 bf16.
// Block 256thr = 4 waves as 2x2: wave = 16 rows x 96 cols. grid = NROWS/32 = 512.
// MODE 0 (feat): A = x (isf dtype), out H0 = bf16(relu(C)); fused stage-1 stats.
// MODE 1 (conv): A = H0 bf16, out Z' = bf16(dis[row] * C).
template<int K, int MODE>
__global__ __launch_bounds__(256) void gemm_mfma(const void* __restrict__ A,
                                                 const __hip_bfloat16* __restrict__ BT,
                                                 const float* __restrict__ bias,
                                                 float* __restrict__ ws) {
    const int isf = ((const int*)ws)[OFF_FLAG];
    int lane = threadIdx.x & 63, w = threadIdx.x >> 6;
    int wr = w & 1, wc = w >> 1;
    int row0 = blockIdx.x*32 + wr*16;
    int col0 = wc*96;
    int m    = lane & 15, quad = lane >> 4;
    f32x4 acc[6];
    #pragma unroll
    for (int t = 0; t < 6; ++t) acc[t] = f32x4{0.f,0.f,0.f,0.f};
    float bv[6];
    #pragma unroll
    for (int t = 0; t < 6; ++t) bv[t] = bias[col0 + t*16 + m];
    #pragma unroll
    for (int kb = 0; kb < K/32; ++kb) {
        short8 a;
        if (MODE == 0 && isf) {
            const float* Ar = (const float*)A + (size_t)(row0+m)*K + kb*32 + quad*8;
            f32x4 v0 = *(const f32x4*)Ar;
            f32x4 v1 = *(const f32x4*)(Ar + 4);
            union { short8 s8; __hip_bfloat16 h[8]; } u;
            #pragma unroll
            for (int e = 0; e < 4; ++e) {
                u.h[e]   = __float2bfloat16(v0[e]);
                u.h[e+4] = __float2bfloat16(v1[e]);
            }
            a = u.s8;
        } else {
            a = *(const short8*)((const __hip_bfloat16*)A +
                                 (size_t)(row0+m)*K + kb*32 + quad*8);
        }
        #pragma unroll
        for (int t = 0; t < 6; ++t) {
            short8 b = *(const short8*)(BT + (size_t)(col0 + t*16+m)*K + kb*32 + quad*8);
            acc[t] = __builtin_amdgcn_mfma_f32_16x16x32_bf16(a, b, acc[t], 0, 0, 0);
        }
    }
    if (MODE == 0) {
        __shared__ float sh[2*HH];
        for (int i = threadIdx.x; i < 2*HH; i += 256) sh[i] = 0.f;
        __syncthreads();
        __hip_bfloat16* H0 = (__hip_bfloat16*)(ws + OFF_H0);
        #pragma unroll
        for (int t = 0; t < 6; ++t) {
            int ch = col0 + t*16 + m;
            float s = 0.f, sq = 0.f;
            #pragma unroll
            for (int r = 0; r < 4; ++r) {
                float o = fmaxf(acc[t][r] + bv[t], 0.f);
                H0[(size_t)(row0 + quad*4 + r)*HH + ch] = __float2bfloat16(o);
                s += o; sq += o*o;
            }
            atomicAdd(&sh[ch], s);
            atomicAdd(&sh[HH + ch], sq);
        }
        __syncthreads();
        float* st = stage_h(ws, 0) + (blockIdx.x & 7)*512;
        if (threadIdx.x < HH) {
            atomicAdd(&st[threadIdx.x], sh[threadIdx.x]);
            atomicAdd(&st[256 + threadIdx.x], sh[HH + threadIdx.x]);
        }
    } else {
        const float* dis = ws + OFF_DIS;
        __hip_bfloat16* Z = (__hip_bfloat16*)(ws + OFF_ZB);
        float sc[4];
        #pragma unroll
        for (int r = 0; r < 4; ++r) sc[r] = dis[row0 + quad*4 + r];
        #pragma unroll
        for (int t = 0; t < 6; ++t)
            #pragma unroll
            for (int r = 0; r < 4; ++r)
                Z[(size_t)(row0 + quad*4 + r)*HH + col0 + t*16 + m] =
                    __float2bfloat16((acc[t][r] + bv[t]) * sc[r]);
    }
}

// H0 = bf16(relu( dis_i * sum_{j in N(i)} Z'[j] + conv_bias[layer] )).
// 4 rows per block (grid NROWS/4, 192 thr). Fused: stats of output (stat_out
// 8-bucket) for layers 0,1; pool sums for layer 2.
__global__ __launch_bounds__(192) void spmm(const void* __restrict__ bias, int layer,
                                            float* __restrict__ stat_out, int is_pool,
                                            float* ws) {
    int tid = threadIdx.x;
    const int isf = ((const int*)ws)[OFF_FLAG];
    const float* dis = ws + OFF_DIS;
    const int* cnt = (const int*)(ws + OFF_CNT);
    const unsigned short* cols = (const unsigned short*)(ws + OFF_COLS);
    const __hip_bfloat16* Z = (const __hip_bfloat16*)(ws + OFF_ZB);
    __hip_bfloat16* H0 = (__hip_bfloat16*)(ws + OFF_H0);
    int r0 = blockIdx.x * 4;
    int base = (r0 >> 10) << 10;
    float bl = ldin(bias, (size_t)layer*HH + tid, isf);
    float s = 0.f, sq = 0.f;
    #pragma unroll
    for (int rr = 0; rr < 4; ++rr) {
        int row = r0 + rr;
        int c = cnt[row];
        const unsigned short* cl = cols + (size_t)row*MAXC;
        float acc = 0.f;
        int k = 0;
        for (; k + 4 <= c; k += 4) {
            int j0 = base + cl[k],   j1 = base + cl[k+1];
            int j2 = base + cl[k+2], j3 = base + cl[k+3];
            acc += bf(Z[(size_t)j0*HH + tid]) + bf(Z[(size_t)j1*HH + tid])
                 + bf(Z[(size_t)j2*HH + tid]) + bf(Z[(size_t)j3*HH + tid]);
        }
        for (; k < c; ++k) acc += bf(Z[(size_t)(base + cl[k])*HH + tid]);
        float o = fmaxf(dis[row]*acc + bl, 0.f);
        H0[(size_t)row*HH + tid] = __float2bfloat16(o);
        s += o; sq += o*o;
    }
    if (is_pool) {
        atomicAdd(&ws[OFF_G + (size_t)(r0 >> 10)*HH + tid], s);
    } else {
        float* st = stat_out + (blockIdx.x & 7)*512;
        atomicAdd(&st[tid], s);
        atomicAdd(&st[256 + tid], sq);
    }
}

// BN -> relu(linear) -> BN -> classifier -> log_softmax. One block, 768 thr.
__global__ __launch_bounds__(768) void tail(
                     const void* __restrict__ fc_g,  const void* __restrict__ fc_b,
                     const void* __restrict__ lin_W, const void* __restrict__ lin_b,
                     const void* __restrict__ hid_g, const void* __restrict__ hid_b,
                     const void* __restrict__ cls_W, const void* __restrict__ cls_b,
                     void* __restrict__ out, const float* ws) {
    __shared__ float g1[BB][HH];
    __shared__ float g2[BB][HH];
    __shared__ __hip_bfloat16 Wl[HH*HH];
    __shared__ float logits[BB][10];
    __shared__ float lse[BB];
    int tid = threadIdx.x;
    const int isf = ((const int*)ws)[OFF_FLAG];
    const float* g = ws + OFF_G;   // sums over N; scale by 1/NN
    if (isf) {
        const float* Wp = (const float*)lin_W;
        for (int i = tid; i < HH*HH; i += 768) Wl[i] = __float2bfloat16(Wp[i]);
    } else {
        const __hip_bfloat16* Wp = (const __hip_bfloat16*)lin_W;
        for (int i = tid; i < HH*HH; i += 768) Wl[i] = Wp[i];
    }
    if (tid < HH) {
        float s = 0.f, sq = 0.f;
        for (int b = 0; b < BB; ++b) {
            float v = g[b*HH + tid] * (1.f/NN);
            s += v; sq += v*v;
        }
        float m = s*(1.f/BB), var = sq*(1.f/BB) - m*m;
        float a = ldin(fc_g, tid, isf) * rsqrtf(var + EPSV);
        float c = ldin(fc_b, tid, isf) - m*a;
        for (int b = 0; b < BB; ++b) g1[b][tid] = g[b*HH + tid]*(1.f/NN)*a + c;
    }
    __syncthreads();
    {
        int n = tid % HH, bg = tid / HH;
        float lb = ldin(lin_b, n, isf);
        float a0 = lb, a1 = lb, a2 = lb, a3 = lb;
        int b0 = bg*4;
        for (int k = 0; k < HH; ++k) {
            float wv = bf(Wl[k*HH + n]);
            a0 += g1[b0+0][k]*wv;
            a1 += g1[b0+1][k]*wv;
            a2 += g1[b0+2][k]*wv;
            a3 += g1[b0+3][k]*wv;
        }
        g2[b0+0][n] = fmaxf(a0, 0.f);
        g2[b0+1][n] = fmaxf(a1, 0.f);
        g2[b0+2][n] = fmaxf(a2, 0.f);
        g2[b0+3][n] = fmaxf(a3, 0.f);
    }
    __syncthreads();
    if (tid < HH) {
        float s = 0.f, sq = 0.f;
        for (int b = 0; b < BB; ++b) { float v = g2[b][tid]; s += v; sq += v*v; }
        float m = s*(1.f/BB), var = sq*(1.f/BB) - m*m;
        float a = ldin(hid_g, tid, isf) * rsqrtf(var + EPSV);
        float c = ldin(hid_b, tid, isf) - m*a;
        for (int b = 0; b < BB; ++b) g2[b][tid] = g2[b][tid]*a + c;
    }
    __syncthreads();
    if (tid < BB*10) {
        int b = tid/10, k = tid%10;
        float acc = ldin(cls_b, k, isf);
        for (int h = 0; h < HH; ++h) acc += g2[b][h] * ldin(cls_W, (size_t)h*10 + k, isf);
        logits[b][k] = acc;
    }
    __syncthreads();
    if (tid < BB) {
        float m = -1e30f;
        for (int k = 0; k < 10; ++k) m = fmaxf(m, logits[tid][k]);
        float s = 0.f;
        for (int k = 0; k < 10; ++k) s += expf(logits[tid][k] - m);
        lse[tid] = m + logf(s);
    }
    __syncthreads();
    if (tid < BB*10) {
        int b = tid/10;
        float v = logits[b][tid%10] - lse[b];
        if (isf) ((float*)out)[tid] = v;
        else     ((__hip_bfloat16*)out)[tid] = __float2bfloat16(v);
    }
}

extern "C" void kernel_launch(void* const* d_in, const int* in_sizes, int n_in,
                              void* d_out, int out_size, void* d_ws, size_t ws_size,
                              hipStream_t stream) {
    const void* x       = d_in[0];
    const void* adj     = d_in[1];
    const void* bnf_g   = d_in[2];
    const void* bnf_b   = d_in[3];
    const void* W_feat  = d_in[4];
    const void* bnc_g   = d_in[5];
    const void* bnc_b   = d_in[6];
    const void* convs_W = d_in[7];
    const void* convs_b = d_in[8];
    const void* fc_g    = d_in[9];
    const void* fc_b    = d_in[10];
    const void* lin_W   = d_in[11];
    const void* lin_b   = d_in[12];
    const void* hid_g   = d_in[13];
    const void* hid_b   = d_in[14];
    const void* cls_W   = d_in[15];
    const void* cls_b   = d_in[16];

    float* ws = (float*)d_ws;
    const __hip_bfloat16* WPF = (const __hip_bfloat16*)(ws + OFF_WPF);
    const __hip_bfloat16* WPC = (const __hip_bfloat16*)(ws + OFF_WPC);

    detect_and_zero<<<1, 256, 0, stream>>>((const unsigned int*)adj, ws);
    phase1<<<NROWS + 256, 256, 0, stream>>>(adj, x, ws);
    prep_feat<<<HH, FF, 0, stream>>>(W_feat, bnf_g, bnf_b, ws);
    gemm_mfma<FF, 0><<<NROWS/32, 256, 0, stream>>>(x, WPF, ws + OFF_BF, ws);
    for (int l = 0; l < 3; ++l) {
        prep_conv<<<HH, HH, 0, stream>>>(convs_W, bnc_g, bnc_b, l, ws);
        gemm_mfma<HH, 1><<<NROWS/32, 256, 0, stream>>>(
            (const void*)(ws + OFF_H0), WPC, ws + OFF_BC, ws);
        spmm<<<NROWS/4, HH, 0, stream>>>(convs_b, l,
            (l < 2) ? stage_h(ws, l + 1) : nullptr, (l == 2) ? 1 : 0, ws);
    }
    tail<<<1, 768, 0, stream>>>(fc_g, fc_b, lin_W, lin_b,
                                hid_g, hid_b, cls_W, cls_b, d_out, ws);
}

// Round 7
// 356.273 us; speedup vs baseline: 2.3636x; 1.0865x over previous
//
#include <hip/hip_runtime.h>
#include <hip/hip_bf16.h>

#define BB 16
#define NN 1024
#define FF 128
#define HH 192
#define NROWS (BB*NN)
#define MAXC 128
#define EPSV 1e-5f

// workspace layout, in float (4B) units (~17 MB total)
constexpr size_t OFF_H0  = 0;                                   // [NROWS*HH] bf16 (h, post-relu)
constexpr size_t OFF_ZB  = OFF_H0 + (size_t)NROWS*HH/2;         // [NROWS*HH] bf16 (Z' = dis_j*(hW'+bias))
constexpr size_t OFF_WPF = OFF_ZB + (size_t)NROWS*HH/2;         // [HH*FF] bf16  feat W'T
constexpr size_t OFF_WPC = OFF_WPF + (size_t)HH*FF/2;           // [HH*HH] bf16  conv W'T (per layer)
constexpr size_t OFF_BF  = OFF_WPC + (size_t)HH*HH/2;           // [HH] f32 feat bias (c@W)
constexpr size_t OFF_BC  = OFF_BF + HH;                         // [HH] f32 conv bias (c@W)
constexpr size_t OFF_DIS = OFF_BC + HH;                         // [NROWS] f32
constexpr size_t OFF_G   = OFF_DIS + NROWS;                     // [BB*HH] f32 pool sums (atomics)
// stats: stage0 (x): 512 single-bucket; stages 1..3 (h): 8 buckets x 512 each
constexpr size_t OFF_ST  = OFF_G + BB*HH;
constexpr size_t ST_SIZE = 512 + 3*8*512;                       // 12800 floats
constexpr size_t OFF_FLAG= OFF_ST + ST_SIZE;                    // 1 int (1 => inputs f32)
constexpr size_t OFF_CNT = OFF_FLAG + 1;                        // [NROWS] int32
constexpr size_t OFF_COLS= OFF_CNT + NROWS;                     // [NROWS*MAXC] u16

typedef __attribute__((ext_vector_type(8))) short short8;   // 8 bf16 in 4 VGPRs
typedef __attribute__((ext_vector_type(4))) float f32x4;
typedef __attribute__((ext_vector_type(4))) unsigned int u32x4;
typedef __attribute__((ext_vector_type(2))) unsigned int u32x2;

static __device__ __forceinline__ float bf(const __hip_bfloat16 v) {
    return __bfloat162float(v);
}
static __device__ __forceinline__ float ldin(const void* p, size_t i, int isf) {
    return isf ? ((const float*)p)[i]
               : __bfloat162float(((const __hip_bfloat16*)p)[i]);
}
static __host__ __device__ __forceinline__ float* stage_h(float* ws, int s /*0..2*/) {
    return ws + OFF_ST + 512 + (size_t)s*8*512;
}
// bf16 pair <-> float helpers (u32 = [hi:ch1 | lo:ch0])
static __device__ __forceinline__ float blo(unsigned int u) {
    union { unsigned int x; float f; } v; v.x = u << 16; return v.f;
}
static __device__ __forceinline__ float bhi(unsigned int u) {
    union { unsigned int x; float f; } v; v.x = u & 0xFFFF0000u; return v.f;
}
static __device__ __forceinline__ unsigned int packbf(float a, float b) {
    union { unsigned int u; __hip_bfloat16 h[2]; } p;
    p.h[0] = __float2bfloat16(a); p.h[1] = __float2bfloat16(b);
    return p.u;
}

// Detect input dtype from adj bit patterns; zero stat accumulators + pool sums.
__global__ void detect_and_zero(const unsigned int* __restrict__ adjw, float* ws) {
    __shared__ int evid;
    int tid = threadIdx.x;
    if (tid == 0) evid = 0;
    __syncthreads();
    int local = 0;
    for (int k = tid; k < 16384; k += 256) {
        unsigned int w = adjw[k];
        if ((w & 0xFFFFu) == 0x3F80u) local++;   // bf16-packed even-index 1.0
    }
    if (local) atomicAdd(&evid, local);
    for (size_t k = tid; k < ST_SIZE; k += 256) ws[OFF_ST + k] = 0.f;
    for (int k = tid; k < BB*HH; k += 256) ws[OFF_G + k] = 0.f;
    __syncthreads();
    if (tid == 0) ((int*)ws)[OFF_FLAG] = (evid == 0) ? 1 : 0;
}

// Role-split kernel: blocks [0,NROWS) build graph rows; blocks [NROWS, NROWS+256)
// compute per-feature stats of x (stage 0).
__global__ __launch_bounds__(256) void phase1(const void* __restrict__ adj,
                                              const void* __restrict__ x, float* ws) {
    const int isf = ((const int*)ws)[OFF_FLAG];
    int tid = threadIdx.x;
    if (blockIdx.x < NROWS) {
        int row = blockIdx.x;
        int i   = row & (NN - 1);
        __shared__ int cnt_s;
        __shared__ unsigned short colbuf[MAXC];
        if (tid == 0) cnt_s = 0;
        __syncthreads();
        int j0 = tid*4;
        unsigned int bits[4];
        if (isf) {
            u32x4 v = *(const u32x4*)((const unsigned int*)adj + (size_t)row*NN + j0);
            bits[0]=v[0]; bits[1]=v[1]; bits[2]=v[2]; bits[3]=v[3];
        } else {
            u32x2 v = *(const u32x2*)((const unsigned short*)adj + (size_t)row*NN + j0);
            bits[0]=(v[0]&0xFFFFu); bits[1]=(v[0]>>16); bits[2]=(v[1]&0xFFFFu); bits[3]=(v[1]>>16);
        }
        #pragma unroll
        for (int e = 0; e < 4; ++e) {
            int j = j0 + e;
            if ((bits[e] << 1) != 0u || j == i) {   // value != +-0  (or self loop)
                int p = atomicAdd(&cnt_s, 1);
                if (p < MAXC) colbuf[p] = (unsigned short)j;
            }
        }
        __syncthreads();
        int c = cnt_s; if (c > MAXC) c = MAXC;
        if (tid == 0) {
            ((int*)(ws + OFF_CNT))[row] = c;
            ws[OFF_DIS + row] = rsqrtf((float)cnt_s);   // deg >= 1 (self loop)
        }
        unsigned short* cols = (unsigned short*)(ws + OFF_COLS);
        for (int k = tid; k < c; k += 256) cols[(size_t)row*MAXC + k] = colbuf[k];
    } else {
        int b2 = blockIdx.x - NROWS;          // 0..255
        int f = tid & (FF-1), half = tid >> 7;
        int r0 = b2*64 + half*32;
        float s = 0.f, sq = 0.f;
        for (int r = 0; r < 32; ++r) {
            float v = ldin(x, (size_t)(r0 + r)*FF + f, isf);
            s += v; sq += v*v;
        }
        atomicAdd(&ws[OFF_ST + f], s);
        atomicAdd(&ws[OFF_ST + 256 + f], sq);
    }
}

// BN-fold for feat layer: W'T[n][k] = a_k * W[k][n] (bf16), biasF[n] = sum_k c_k W[k][n].
__global__ void prep_feat(const void* __restrict__ W_feat,
                          const void* __restrict__ gg, const void* __restrict__ bb,
                          float* ws) {
    const int isf = ((const int*)ws)[OFF_FLAG];
    int n = blockIdx.x, k = threadIdx.x;
    const float* st = ws + OFF_ST;
    float m   = st[k] * (1.f/NROWS);
    float var = st[256+k] * (1.f/NROWS) - m*m;
    float a   = ldin(gg, k, isf) * rsqrtf(var + EPSV);
    float c   = ldin(bb, k, isf) - m*a;
    float wv  = ldin(W_feat, (size_t)k*HH + n, isf);
    ((__hip_bfloat16*)(ws + OFF_WPF))[(size_t)n*FF + k] = __float2bfloat16(a*wv);
    __shared__ float red[FF];
    red[k] = c*wv;
    __syncthreads();
    for (int s = FF/2; s > 0; s >>= 1) {
        if (k < s) red[k] += red[k + s];
        __syncthreads();
    }
    if (k == 0) ws[OFF_BF + n] = red[0];
}

// BN-fold for conv layer l (reads 8-bucket stats of stage l).
__global__ void prep_conv(const void* __restrict__ convs_W,
                          const void* __restrict__ gg, const void* __restrict__ bb,
                          int layer, float* ws) {
    const int isf = ((const int*)ws)[OFF_FLAG];
    int n = blockIdx.x, k = threadIdx.x;
    const float* st = stage_h(ws, layer);
    float s = 0.f, sq = 0.f;
    #pragma unroll
    for (int bkt = 0; bkt < 8; ++bkt) {
        s  += st[bkt*512 + k];
        sq += st[bkt*512 + 256 + k];
    }
    float m   = s * (1.f/NROWS);
    float var = sq * (1.f/NROWS) - m*m;
    float a   = ldin(gg, (size_t)layer*HH + k, isf) * rsqrtf(var + EPSV);
    float c   = ldin(bb, (size_t)layer*HH + k, isf) - m*a;
    float wv  = ldin(convs_W, (size_t)layer*HH*HH + (size_t)k*HH + n, isf);
    ((__hip_bfloat16*)(ws + OFF_WPC))[(size_t)n*HH + k] = __float2bfloat16(a*wv);
    __shared__ float red[HH];
    red[k] = c*wv;
    __syncthreads();
    if (k < 96) red[k] += red[k + 96];
    __syncthreads();
    for (int s2 = 48; s2 >= 3; s2 >>= 1) {
        if (k < s2) red[k] += red[k + s2];
        __syncthreads();
    }
    if (k == 0) ws[OFF_BC + n] = red[0] + red[1] + red[2];
}

// C = A[M x K] @ W'T[N x K]^T + bias via MFMA 16x16x32 bf16.
// Block 256thr = 4 waves as 2x2: wave = 16 rows x 96 cols. grid = NROWS/32 = 512.
// XCD-locality swizzle: batch = blockIdx & 15 (XCD blockIdx%8 owns 2 batches).
// MODE 0 (feat): A = x (isf dtype), out H0 = bf16(relu(C)); fused stage-1 stats.
// MODE 1 (conv): A = H0 bf16, out Z' = bf16(dis[row] * C).
template<int K, int MODE>
__global__ __launch_bounds__(256) void gemm_mfma(const void* __restrict__ A,
                                                 const __hip_bfloat16* __restrict__ BT,
                                                 const float* __restrict__ bias,
                                                 float* __restrict__ ws) {
    const int isf = ((const int*)ws)[OFF_FLAG];
    int lane = threadIdx.x & 63, w = threadIdx.x >> 6;
    int wr = w & 1, wc = w >> 1;
    int bi = blockIdx.x;
    int batch = bi & 15, seg = bi >> 4;               // seg 0..31
    int row0 = batch*NN + seg*32 + wr*16;
    int col0 = wc*96;
    int m    = lane & 15, quad = lane >> 4;
    f32x4 acc[6];
    #pragma unroll
    for (int t = 0; t < 6; ++t) acc[t] = f32x4{0.f,0.f,0.f,0.f};
    float bv[6];
    #pragma unroll
    for (int t = 0; t < 6; ++t) bv[t] = bias[col0 + t*16 + m];
    #pragma unroll
    for (int kb = 0; kb < K/32; ++kb) {
        short8 a;
        if (MODE == 0 && isf) {
            const float* Ar = (const float*)A + (size_t)(row0+m)*K + kb*32 + quad*8;
            f32x4 v0 = *(const f32x4*)Ar;
            f32x4 v1 = *(const f32x4*)(Ar + 4);
            union { short8 s8; __hip_bfloat16 h[8]; } u;
            #pragma unroll
            for (int e = 0; e < 4; ++e) {
                u.h[e]   = __float2bfloat16(v0[e]);
                u.h[e+4] = __float2bfloat16(v1[e]);
            }
            a = u.s8;
        } else {
            a = *(const short8*)((const __hip_bfloat16*)A +
                                 (size_t)(row0+m)*K + kb*32 + quad*8);
        }
        #pragma unroll
        for (int t = 0; t < 6; ++t) {
            short8 b = *(const short8*)(BT + (size_t)(col0 + t*16+m)*K + kb*32 + quad*8);
            acc[t] = __builtin_amdgcn_mfma_f32_16x16x32_bf16(a, b, acc[t], 0, 0, 0);
        }
    }
    if (MODE == 0) {
        __shared__ float sh[2*HH];
        for (int i = threadIdx.x; i < 2*HH; i += 256) sh[i] = 0.f;
        __syncthreads();
        __hip_bfloat16* H0 = (__hip_bfloat16*)(ws + OFF_H0);
        #pragma unroll
        for (int t = 0; t < 6; ++t) {
            int ch = col0 + t*16 + m;
            float s = 0.f, sq = 0.f;
            #pragma unroll
            for (int r = 0; r < 4; ++r) {
                float o = fmaxf(acc[t][r] + bv[t], 0.f);
                H0[(size_t)(row0 + quad*4 + r)*HH + ch] = __float2bfloat16(o);
                s += o; sq += o*o;
            }
            atomicAdd(&sh[ch], s);
            atomicAdd(&sh[HH + ch], sq);
        }
        __syncthreads();
        float* st = stage_h(ws, 0) + (bi & 7)*512;
        if (threadIdx.x < HH) {
            atomicAdd(&st[threadIdx.x], sh[threadIdx.x]);
            atomicAdd(&st[256 + threadIdx.x], sh[HH + threadIdx.x]);
        }
    } else {
        const float* dis = ws + OFF_DIS;
        __hip_bfloat16* Z = (__hip_bfloat16*)(ws + OFF_ZB);
        float sc[4];
        #pragma unroll
        for (int r = 0; r < 4; ++r) sc[r] = dis[row0 + quad*4 + r];
        #pragma unroll
        for (int t = 0; t < 6; ++t)
            #pragma unroll
            for (int r = 0; r < 4; ++r)
                Z[(size_t)(row0 + quad*4 + r)*HH + col0 + t*16 + m] =
                    __float2bfloat16((acc[t][r] + bv[t]) * sc[r]);
    }
}

// H0 = bf16(relu( dis_i * sum_{j in N(i)} Z'[j] + conv_bias[layer] )).
// 384 thr = 4 rows x 96 thr; thread handles channel pair (2t, 2t+1) via u32 loads.
// grid NROWS/4 with batch swizzle (batch = blockIdx & 15 -> same XCD as gemm).
// Fused: stats of output (8-bucket) for layers 0,1; pool sums for layer 2.
__global__ __launch_bounds__(384) void spmm(const void* __restrict__ bias, int layer,
                                            float* __restrict__ stat_out, int is_pool,
                                            float* ws) {
    int tid = threadIdx.x;
    int rl  = tid / 96;            // 0..3
    int t   = tid - rl*96;         // 0..95 -> channels 2t, 2t+1
    const int isf = ((const int*)ws)[OFF_FLAG];
    int bi = blockIdx.x;
    int batch = bi & 15, seg = bi >> 4;      // seg 0..255
    int row  = batch*NN + seg*4 + rl;
    int base = batch*NN;
    const float* dis = ws + OFF_DIS;
    int c = ((const int*)(ws + OFF_CNT))[row];
    const unsigned short* cl = (const unsigned short*)(ws + OFF_COLS) + (size_t)row*MAXC;
    const unsigned int* Zu = (const unsigned int*)(ws + OFF_ZB);
    __shared__ float sh_s[HH];
    __shared__ float sh_q[HH];
    if (!is_pool) {
        for (int i = tid; i < HH; i += 384) { sh_s[i] = 0.f; sh_q[i] = 0.f; }
    } else {
        for (int i = tid; i < HH; i += 384) sh_s[i] = 0.f;
    }
    __syncthreads();
    float a0 = 0.f, a1 = 0.f;
    int k = 0;
    for (; k + 8 <= c; k += 8) {
        u32x4 cw = *(const u32x4*)(cl + k);    // 8 u16 col indices
        int j[8];
        j[0] = (int)(cw[0] & 0xFFFFu); j[1] = (int)(cw[0] >> 16);
        j[2] = (int)(cw[1] & 0xFFFFu); j[3] = (int)(cw[1] >> 16);
        j[4] = (int)(cw[2] & 0xFFFFu); j[5] = (int)(cw[2] >> 16);
        j[6] = (int)(cw[3] & 0xFFFFu); j[7] = (int)(cw[3] >> 16);
        unsigned int z[8];
        #pragma unroll
        for (int e = 0; e < 8; ++e)
            z[e] = Zu[(size_t)(base + j[e])*96 + t];
        #pragma unroll
        for (int e = 0; e < 8; ++e) { a0 += blo(z[e]); a1 += bhi(z[e]); }
    }
    for (; k < c; ++k) {
        unsigned int z = Zu[(size_t)(base + (int)cl[k])*96 + t];
        a0 += blo(z); a1 += bhi(z);
    }
    float d  = dis[row];
    float b0 = ldin(bias, (size_t)layer*HH + 2*t,     isf);
    float b1 = ldin(bias, (size_t)layer*HH + 2*t + 1, isf);
    float o0 = fmaxf(d*a0 + b0, 0.f);
    float o1 = fmaxf(d*a1 + b1, 0.f);
    ((unsigned int*)(ws + OFF_H0))[(size_t)row*96 + t] = packbf(o0, o1);
    if (is_pool) {
        atomicAdd(&sh_s[2*t],     o0);
        atomicAdd(&sh_s[2*t + 1], o1);
        __syncthreads();
        if (tid < HH) atomicAdd(&ws[OFF_G + (size_t)batch*HH + tid], sh_s[tid]);
    } else {
        atomicAdd(&sh_s[2*t],     o0);
        atomicAdd(&sh_s[2*t + 1], o1);
        atomicAdd(&sh_q[2*t],     o0*o0);
        atomicAdd(&sh_q[2*t + 1], o1*o1);
        __syncthreads();
        float* st = stat_out + (bi & 7)*512;
        if (tid < HH) {
            atomicAdd(&st[tid],       sh_s[tid]);
            atomicAdd(&st[256 + tid], sh_q[tid]);
        }
    }
}

// BN -> relu(linear) -> BN -> classifier -> log_softmax. One block, 768 thr.
__global__ __launch_bounds__(768) void tail(
                     const void* __restrict__ fc_g,  const void* __restrict__ fc_b,
                     const void* __restrict__ lin_W, const void* __restrict__ lin_b,
                     const void* __restrict__ hid_g, const void* __restrict__ hid_b,
                     const void* __restrict__ cls_W, const void* __restrict__ cls_b,
                     void* __restrict__ out, const float* ws) {
    __shared__ float g1[BB][HH];
    __shared__ float g2[BB][HH];
    __shared__ __hip_bfloat16 Wl[HH*HH];
    __shared__ float logits[BB][10];
    __shared__ float lse[BB];
    int tid = threadIdx.x;
    const int isf = ((const int*)ws)[OFF_FLAG];
    const float* g = ws + OFF_G;   // sums over N; scale by 1/NN
    if (isf) {
        const float* Wp = (const float*)lin_W;
        for (int i = tid; i < HH*HH; i += 768) Wl[i] = __float2bfloat16(Wp[i]);
    } else {
        const __hip_bfloat16* Wp = (const __hip_bfloat16*)lin_W;
        for (int i = tid; i < HH*HH; i += 768) Wl[i] = Wp[i];
    }
    if (tid < HH) {
        float s = 0.f, sq = 0.f;
        for (int b = 0; b < BB; ++b) {
            float v = g[b*HH + tid] * (1.f/NN);
            s += v; sq += v*v;
        }
        float m = s*(1.f/BB), var = sq*(1.f/BB) - m*m;
        float a = ldin(fc_g, tid, isf) * rsqrtf(var + EPSV);
        float c = ldin(fc_b, tid, isf) - m*a;
        for (int b = 0; b < BB; ++b) g1[b][tid] = g[b*HH + tid]*(1.f/NN)*a + c;
    }
    __syncthreads();
    {
        int n = tid % HH, bg = tid / HH;
        float lb = ldin(lin_b, n, isf);
        float a0 = lb, a1 = lb, a2 = lb, a3 = lb;
        int b0 = bg*4;
        for (int k = 0; k < HH; ++k) {
            float wv = bf(Wl[k*HH + n]);
            a0 += g1[b0+0][k]*wv;
            a1 += g1[b0+1][k]*wv;
            a2 += g1[b0+2][k]*wv;
            a3 += g1[b0+3][k]*wv;
        }
        g2[b0+0][n] = fmaxf(a0, 0.f);
        g2[b0+1][n] = fmaxf(a1, 0.f);
        g2[b0+2][n] = fmaxf(a2, 0.f);
        g2[b0+3][n] = fmaxf(a3, 0.f);
    }
    __syncthreads();
    if (tid < HH) {
        float s = 0.f, sq = 0.f;
        for (int b = 0; b < BB; ++b) { float v = g2[b][tid]; s += v; sq += v*v; }
        float m = s*(1.f/BB), var = sq*(1.f/BB) - m*m;
        float a = ldin(hid_g, tid, isf) * rsqrtf(var + EPSV);
        float c = ldin(hid_b, tid, isf) - m*a;
        for (int b = 0; b < BB; ++b) g2[b][tid] = g2[b][tid]*a + c;
    }
    __syncthreads();
    if (tid < BB*10) {
        int b = tid/10, k = tid%10;
        float acc = ldin(cls_b, k, isf);
        for (int h = 0; h < HH; ++h) acc += g2[b][h] * ldin(cls_W, (size_t)h*10 + k, isf);
        logits[b][k] = acc;
    }
    __syncthreads();
    if (tid < BB) {
        float m = -1e30f;
        for (int k = 0; k < 10; ++k) m = fmaxf(m, logits[tid][k]);
        float s = 0.f;
        for (int k = 0; k < 10; ++k) s += expf(logits[tid][k] - m);
        lse[tid] = m + logf(s);
    }
    __syncthreads();
    if (tid < BB*10) {
        int b = tid/10;
        float v = logits[b][tid%10] - lse[b];
        if (isf) ((float*)out)[tid] = v;
        else     ((__hip_bfloat16*)out)[tid] = __float2bfloat16(v);
    }
}

extern "C" void kernel_launch(void* const* d_in, const int* in_sizes, int n_in,
                              void* d_out, int out_size, void* d_ws, size_t ws_size,
                              hipStream_t stream) {
    const void* x       = d_in[0];
    const void* adj     = d_in[1];
    const void* bnf_g   = d_in[2];
    const void* bnf_b   = d_in[3];
    const void* W_feat  = d_in[4];
    const void* bnc_g   = d_in[5];
    const void* bnc_b   = d_in[6];
    const void* convs_W = d_in[7];
    const void* convs_b = d_in[8];
    const void* fc_g    = d_in[9];
    const void* fc_b    = d_in[10];
    const void* lin_W   = d_in[11];
    const void* lin_b   = d_in[12];
    const void* hid_g   = d_in[13];
    const void* hid_b   = d_in[14];
    const void* cls_W   = d_in[15];
    const void* cls_b   = d_in[16];

    float* ws = (float*)d_ws;
    const __hip_bfloat16* WPF = (const __hip_bfloat16*)(ws + OFF_WPF);
    const __hip_bfloat16* WPC = (const __hip_bfloat16*)(ws + OFF_WPC);

    detect_and_zero<<<1, 256, 0, stream>>>((const unsigned int*)adj, ws);
    phase1<<<NROWS + 256, 256, 0, stream>>>(adj, x, ws);
    prep_feat<<<HH, FF, 0, stream>>>(W_feat, bnf_g, bnf_b, ws);
    gemm_mfma<FF, 0><<<NROWS/32, 256, 0, stream>>>(x, WPF, ws + OFF_BF, ws);
    for (int l = 0; l < 3; ++l) {
        prep_conv<<<HH, HH, 0, stream>>>(convs_W, bnc_g, bnc_b, l, ws);
        gemm_mfma<HH, 1><<<NROWS/32, 256, 0, stream>>>(
            (const void*)(ws + OFF_H0), WPC, ws + OFF_BC, ws);
        spmm<<<NROWS/4, 384, 0, stream>>>(convs_b, l,
            (l < 2) ? stage_h(ws, l + 1) : nullptr, (l == 2) ? 1 : 0, ws);
    }
    tail<<<1, 768, 0, stream>>>(fc_g, fc_b, lin_W, lin_b,
                                hid_g, hid_b, cls_W, cls_b, d_out, ws);
}

// Round 8
// 331.699 us; speedup vs baseline: 2.5387x; 1.0741x over previous
//
#include <hip/hip_runtime.h>
#include <hip/hip_bf16.h>

#define BB 16
#define NN 1024
#define FF 128
#define HH 192
#define NROWS (BB*NN)
#define MAXC 128
#define EPSV 1e-5f

// workspace layout, in float (4B) units (~17 MB total)
constexpr size_t OFF_H0  = 0;                                   // [NROWS*HH] bf16 (h, post-relu)
constexpr size_t OFF_ZB  = OFF_H0 + (size_t)NROWS*HH/2;         // [NROWS*HH] bf16 (Z' = dis_j*(hW'+bias))
constexpr size_t OFF_WPF = OFF_ZB + (size_t)NROWS*HH/2;         // [HH*FF] bf16  feat W'T
constexpr size_t OFF_WPC = OFF_WPF + (size_t)HH*FF/2;           // [HH*HH] bf16  conv W'T (per layer)
constexpr size_t OFF_BF  = OFF_WPC + (size_t)HH*HH/2;           // [HH] f32 feat bias (c@W)
constexpr size_t OFF_BC  = OFF_BF + HH;                         // [HH] f32 conv bias (c@W)
constexpr size_t OFF_DIS = OFF_BC + HH;                         // [NROWS] f32
constexpr size_t OFF_G   = OFF_DIS + NROWS;                     // [BB*HH] f32 pool sums (atomics)
// stats: stage0 (x): 512 single-bucket; stages 1..3 (h): 8 buckets x 512 each
constexpr size_t OFF_ST  = OFF_G + BB*HH;
constexpr size_t ST_SIZE = 512 + 3*8*512;                       // 12800 floats
constexpr size_t OFF_FLAG= OFF_ST + ST_SIZE;                    // 1 int (1 => inputs f32)
constexpr size_t OFF_CNT = OFF_FLAG + 1;                        // [NROWS] int32
constexpr size_t OFF_COLS= OFF_CNT + NROWS;                     // [NROWS*MAXC] u16

typedef __attribute__((ext_vector_type(8))) short short8;   // 8 bf16 in 4 VGPRs
typedef __attribute__((ext_vector_type(4))) float f32x4;
typedef __attribute__((ext_vector_type(4))) unsigned int u32x4;
typedef __attribute__((ext_vector_type(2))) unsigned int u32x2;

static __device__ __forceinline__ float bf(const __hip_bfloat16 v) {
    return __bfloat162float(v);
}
static __device__ __forceinline__ float ldin(const void* p, size_t i, int isf) {
    return isf ? ((const float*)p)[i]
               : __bfloat162float(((const __hip_bfloat16*)p)[i]);
}
static __host__ __device__ __forceinline__ float* stage_h(float* ws, int s /*0..2*/) {
    return ws + OFF_ST + 512 + (size_t)s*8*512;
}
// bf16 pair <-> float helpers (u32 = [hi:ch1 | lo:ch0])
static __device__ __forceinline__ float blo(unsigned int u) {
    union { unsigned int x; float f; } v; v.x = u << 16; return v.f;
}
static __device__ __forceinline__ float bhi(unsigned int u) {
    union { unsigned int x; float f; } v; v.x = u & 0xFFFF0000u; return v.f;
}
static __device__ __forceinline__ unsigned int packbf(float a, float b) {
    union { unsigned int u; __hip_bfloat16 h[2]; } p;
    p.h[0] = __float2bfloat16(a); p.h[1] = __float2bfloat16(b);
    return p.u;
}

// Detect input dtype from adj bit patterns; zero stat accumulators + pool sums.
__global__ void detect_and_zero(const unsigned int* __restrict__ adjw, float* ws) {
    __shared__ int evid;
    int tid = threadIdx.x;
    if (tid == 0) evid = 0;
    __syncthreads();
    int local = 0;
    for (int k = tid; k < 16384; k += 256) {
        unsigned int w = adjw[k];
        if ((w & 0xFFFFu) == 0x3F80u) local++;   // bf16-packed even-index 1.0
    }
    if (local) atomicAdd(&evid, local);
    for (size_t k = tid; k < ST_SIZE; k += 256) ws[OFF_ST + k] = 0.f;
    for (int k = tid; k < BB*HH; k += 256) ws[OFF_G + k] = 0.f;
    __syncthreads();
    if (tid == 0) ((int*)ws)[OFF_FLAG] = (evid == 0) ? 1 : 0;
}

// Role-split kernel: blocks [0,NROWS) build graph rows; blocks [NROWS, NROWS+256)
// compute per-feature stats of x (stage 0).
__global__ __launch_bounds__(256) void phase1(const void* __restrict__ adj,
                                              const void* __restrict__ x, float* ws) {
    const int isf = ((const int*)ws)[OFF_FLAG];
    int tid = threadIdx.x;
    if (blockIdx.x < NROWS) {
        int row = blockIdx.x;
        int i   = row & (NN - 1);
        __shared__ int cnt_s;
        __shared__ unsigned short colbuf[MAXC];
        if (tid == 0) cnt_s = 0;
        __syncthreads();
        int j0 = tid*4;
        unsigned int bits[4];
        if (isf) {
            u32x4 v = *(const u32x4*)((const unsigned int*)adj + (size_t)row*NN + j0);
            bits[0]=v[0]; bits[1]=v[1]; bits[2]=v[2]; bits[3]=v[3];
        } else {
            u32x2 v = *(const u32x2*)((const unsigned short*)adj + (size_t)row*NN + j0);
            bits[0]=(v[0]&0xFFFFu); bits[1]=(v[0]>>16); bits[2]=(v[1]&0xFFFFu); bits[3]=(v[1]>>16);
        }
        #pragma unroll
        for (int e = 0; e < 4; ++e) {
            int j = j0 + e;
            if ((bits[e] << 1) != 0u || j == i) {   // value != +-0  (or self loop)
                int p = atomicAdd(&cnt_s, 1);
                if (p < MAXC) colbuf[p] = (unsigned short)j;
            }
        }
        __syncthreads();
        int c = cnt_s; if (c > MAXC) c = MAXC;
        if (tid == 0) {
            ((int*)(ws + OFF_CNT))[row] = c;
            ws[OFF_DIS + row] = rsqrtf((float)cnt_s);   // deg >= 1 (self loop)
        }
        unsigned short* cols = (unsigned short*)(ws + OFF_COLS);
        for (int k = tid; k < c; k += 256) cols[(size_t)row*MAXC + k] = colbuf[k];
    } else {
        int b2 = blockIdx.x - NROWS;          // 0..255
        int f = tid & (FF-1), half = tid >> 7;
        int r0 = b2*64 + half*32;
        float s = 0.f, sq = 0.f;
        for (int r = 0; r < 32; ++r) {
            float v = ldin(x, (size_t)(r0 + r)*FF + f, isf);
            s += v; sq += v*v;
        }
        atomicAdd(&ws[OFF_ST + f], s);
        atomicAdd(&ws[OFF_ST + 256 + f], sq);
    }
}

// BN-fold for feat layer: W'T[n][k] = a_k * W[k][n] (bf16), biasF[n] = sum_k c_k W[k][n].
__global__ void prep_feat(const void* __restrict__ W_feat,
                          const void* __restrict__ gg, const void* __restrict__ bb,
                          float* ws) {
    const int isf = ((const int*)ws)[OFF_FLAG];
    int n = blockIdx.x, k = threadIdx.x;
    const float* st = ws + OFF_ST;
    float m   = st[k] * (1.f/NROWS);
    float var = st[256+k] * (1.f/NROWS) - m*m;
    float a   = ldin(gg, k, isf) * rsqrtf(var + EPSV);
    float c   = ldin(bb, k, isf) - m*a;
    float wv  = ldin(W_feat, (size_t)k*HH + n, isf);
    ((__hip_bfloat16*)(ws + OFF_WPF))[(size_t)n*FF + k] = __float2bfloat16(a*wv);
    __shared__ float red[FF];
    red[k] = c*wv;
    __syncthreads();
    for (int s = FF/2; s > 0; s >>= 1) {
        if (k < s) red[k] += red[k + s];
        __syncthreads();
    }
    if (k == 0) ws[OFF_BF + n] = red[0];
}

// BN-fold for conv layer l (reads 8-bucket stats of stage l).
__global__ void prep_conv(const void* __restrict__ convs_W,
                          const void* __restrict__ gg, const void* __restrict__ bb,
                          int layer, float* ws) {
    const int isf = ((const int*)ws)[OFF_FLAG];
    int n = blockIdx.x, k = threadIdx.x;
    const float* st = stage_h(ws, layer);
    float s = 0.f, sq = 0.f;
    #pragma unroll
    for (int bkt = 0; bkt < 8; ++bkt) {
        s  += st[bkt*512 + k];
        sq += st[bkt*512 + 256 + k];
    }
    float m   = s * (1.f/NROWS);
    float var = sq * (1.f/NROWS) - m*m;
    float a   = ldin(gg, (size_t)layer*HH + k, isf) * rsqrtf(var + EPSV);
    float c   = ldin(bb, (size_t)layer*HH + k, isf) - m*a;
    float wv  = ldin(convs_W, (size_t)layer*HH*HH + (size_t)k*HH + n, isf);
    ((__hip_bfloat16*)(ws + OFF_WPC))[(size_t)n*HH + k] = __float2bfloat16(a*wv);
    __shared__ float red[HH];
    red[k] = c*wv;
    __syncthreads();
    if (k < 96) red[k] += red[k + 96];
    __syncthreads();
    for (int s2 = 48; s2 >= 3; s2 >>= 1) {
        if (k < s2) red[k] += red[k + s2];
        __syncthreads();
    }
    if (k == 0) ws[OFF_BC + n] = red[0] + red[1] + red[2];
}

// C = A[M x K] @ W'T[N x K]^T + bias via MFMA 16x16x32 bf16.
// Block 256thr = 4 waves as 2x2: wave = 16 rows x 96 cols. grid = NROWS/32 = 512.
// XCD-locality swizzle: batch = blockIdx & 15 (XCD blockIdx%8 owns 2 batches).
// MODE 0 (feat): A = x (isf dtype), out H0 = bf16(relu(C)); fused stage-1 stats.
// MODE 1 (conv): A = H0 bf16, out Z' = bf16(dis[row] * C).
template<int K, int MODE>
__global__ __launch_bounds__(256) void gemm_mfma(const void* __restrict__ A,
                                                 const __hip_bfloat16* __restrict__ BT,
                                                 const float* __restrict__ bias,
                                                 float* __restrict__ ws) {
    const int isf = ((const int*)ws)[OFF_FLAG];
    int lane = threadIdx.x & 63, w = threadIdx.x >> 6;
    int wr = w & 1, wc = w >> 1;
    int bi = blockIdx.x;
    int batch = bi & 15, seg = bi >> 4;               // seg 0..31
    int row0 = batch*NN + seg*32 + wr*16;
    int col0 = wc*96;
    int m    = lane & 15, quad = lane >> 4;
    f32x4 acc[6];
    #pragma unroll
    for (int t = 0; t < 6; ++t) acc[t] = f32x4{0.f,0.f,0.f,0.f};
    float bv[6];
    #pragma unroll
    for (int t = 0; t < 6; ++t) bv[t] = bias[col0 + t*16 + m];
    #pragma unroll
    for (int kb = 0; kb < K/32; ++kb) {
        short8 a;
        if (MODE == 0 && isf) {
            const float* Ar = (const float*)A + (size_t)(row0+m)*K + kb*32 + quad*8;
            f32x4 v0 = *(const f32x4*)Ar;
            f32x4 v1 = *(const f32x4*)(Ar + 4);
            union { short8 s8; __hip_bfloat16 h[8]; } u;
            #pragma unroll
            for (int e = 0; e < 4; ++e) {
                u.h[e]   = __float2bfloat16(v0[e]);
                u.h[e+4] = __float2bfloat16(v1[e]);
            }
            a = u.s8;
        } else {
            a = *(const short8*)((const __hip_bfloat16*)A +
                                 (size_t)(row0+m)*K + kb*32 + quad*8);
        }
        #pragma unroll
        for (int t = 0; t < 6; ++t) {
            short8 b = *(const short8*)(BT + (size_t)(col0 + t*16+m)*K + kb*32 + quad*8);
            acc[t] = __builtin_amdgcn_mfma_f32_16x16x32_bf16(a, b, acc[t], 0, 0, 0);
        }
    }
    if (MODE == 0) {
        __shared__ float sh[2*HH];
        for (int i = threadIdx.x; i < 2*HH; i += 256) sh[i] = 0.f;
        __syncthreads();
        __hip_bfloat16* H0 = (__hip_bfloat16*)(ws + OFF_H0);
        #pragma unroll
        for (int t = 0; t < 6; ++t) {
            int ch = col0 + t*16 + m;
            float s = 0.f, sq = 0.f;
            #pragma unroll
            for (int r = 0; r < 4; ++r) {
                float o = fmaxf(acc[t][r] + bv[t], 0.f);
                H0[(size_t)(row0 + quad*4 + r)*HH + ch] = __float2bfloat16(o);
                s += o; sq += o*o;
            }
            atomicAdd(&sh[ch], s);
            atomicAdd(&sh[HH + ch], sq);
        }
        __syncthreads();
        float* st = stage_h(ws, 0) + (bi & 7)*512;
        if (threadIdx.x < HH) {
            atomicAdd(&st[threadIdx.x], sh[threadIdx.x]);
            atomicAdd(&st[256 + threadIdx.x], sh[HH + threadIdx.x]);
        }
    } else {
        const float* dis = ws + OFF_DIS;
        __hip_bfloat16* Z = (__hip_bfloat16*)(ws + OFF_ZB);
        float sc[4];
        #pragma unroll
        for (int r = 0; r < 4; ++r) sc[r] = dis[row0 + quad*4 + r];
        #pragma unroll
        for (int t = 0; t < 6; ++t)
            #pragma unroll
            for (int r = 0; r < 4; ++r)
                Z[(size_t)(row0 + quad*4 + r)*HH + col0 + t*16 + m] =
                    __float2bfloat16((acc[t][r] + bv[t]) * sc[r]);
    }
}

// LDS-staged SpMM: H0 = bf16(relu( dis_i * sum_{j in N(i)} Z'[j] + bias )).
// grid 192 = batch(16) x [slice(6) x half(2)]; block 512 thr.
// Stages Z[batch][:, c0:c0+32] (64 KB) into LDS; gathers via ds_read_b64.
// Thread = (rslot 0..63, chunk d 0..7 -> 4 channels). 8 row-iterations.
// Fused stats (8-bucket) for layers 0,1; pool sums for layer 2, via wave shuffles.
__global__ __launch_bounds__(512) void spmm(const void* __restrict__ bias, int layer,
                                            float* __restrict__ stat_out, int is_pool,
                                            float* ws) {
    __shared__ unsigned int Zs[NN*16];   // exactly 64 KB
    const int isf = ((const int*)ws)[OFF_FLAG];
    int tid = threadIdx.x;
    int bi = blockIdx.x;
    int batch = bi & 15;
    int rest  = bi >> 4;          // 0..11
    int slice = rest % 6;         // channel slice: c0 = slice*32
    int half  = rest / 6;         // rows [half*512, half*512+512)
    int c0 = slice*32;
    const unsigned int* Zu = (const unsigned int*)(ws + OFF_ZB)
                             + (size_t)batch*NN*96 + c0/2;
    for (int i = tid; i < NN*16; i += 512) {
        int r = i >> 4, u = i & 15;
        Zs[i] = Zu[(size_t)r*96 + u];
    }
    __syncthreads();
    int d = tid & 7, rslot = tid >> 3;
    const float* dis = ws + OFF_DIS;
    const int* cnt = (const int*)(ws + OFF_CNT);
    const unsigned short* cols = (const unsigned short*)(ws + OFF_COLS);
    unsigned int* H0u = (unsigned int*)(ws + OFF_H0);
    float bch[4];
    #pragma unroll
    for (int e = 0; e < 4; ++e)
        bch[e] = ldin(bias, (size_t)layer*HH + c0 + d*4 + e, isf);
    float s_acc[4] = {0.f,0.f,0.f,0.f}, q_acc[4] = {0.f,0.f,0.f,0.f};
    for (int it = 0; it < 8; ++it) {
        int row = batch*NN + half*512 + it*64 + rslot;
        int c = cnt[row];
        const unsigned short* cl = cols + (size_t)row*MAXC;
        float a0=0.f, a1=0.f, a2=0.f, a3=0.f;
        int k = 0;
        for (; k + 8 <= c; k += 8) {
            u32x4 cw = *(const u32x4*)(cl + k);
            int j[8];
            j[0]=(int)(cw[0]&0xFFFFu); j[1]=(int)(cw[0]>>16);
            j[2]=(int)(cw[1]&0xFFFFu); j[3]=(int)(cw[1]>>16);
            j[4]=(int)(cw[2]&0xFFFFu); j[5]=(int)(cw[2]>>16);
            j[6]=(int)(cw[3]&0xFFFFu); j[7]=(int)(cw[3]>>16);
            u32x2 z[8];
            #pragma unroll
            for (int e = 0; e < 8; ++e)
                z[e] = *(const u32x2*)(&Zs[j[e]*16 + d*2]);
            #pragma unroll
            for (int e = 0; e < 8; ++e) {
                a0 += blo(z[e][0]); a1 += bhi(z[e][0]);
                a2 += blo(z[e][1]); a3 += bhi(z[e][1]);
            }
        }
        for (; k < c; ++k) {
            u32x2 z = *(const u32x2*)(&Zs[(int)cl[k]*16 + d*2]);
            a0 += blo(z[0]); a1 += bhi(z[0]);
            a2 += blo(z[1]); a3 += bhi(z[1]);
        }
        float dd = dis[row];
        float o0 = fmaxf(dd*a0 + bch[0], 0.f);
        float o1 = fmaxf(dd*a1 + bch[1], 0.f);
        float o2 = fmaxf(dd*a2 + bch[2], 0.f);
        float o3 = fmaxf(dd*a3 + bch[3], 0.f);
        u32x2 outw; outw[0] = packbf(o0,o1); outw[1] = packbf(o2,o3);
        *(u32x2*)(&H0u[(size_t)row*96 + c0/2 + d*2]) = outw;
        s_acc[0]+=o0; s_acc[1]+=o1; s_acc[2]+=o2; s_acc[3]+=o3;
        q_acc[0]+=o0*o0; q_acc[1]+=o1*o1; q_acc[2]+=o2*o2; q_acc[3]+=o3*o3;
    }
    // reduce over rslot within each wave (lanes differing in bits 3..5 share d)
    #pragma unroll
    for (int e = 0; e < 4; ++e) {
        #pragma unroll
        for (int mask = 8; mask < 64; mask <<= 1) {
            s_acc[e] += __shfl_xor(s_acc[e], mask, 64);
            q_acc[e] += __shfl_xor(q_acc[e], mask, 64);
        }
    }
    if ((tid & 63) < 8) {
        if (is_pool) {
            #pragma unroll
            for (int e = 0; e < 4; ++e)
                atomicAdd(&ws[OFF_G + (size_t)batch*HH + c0 + d*4 + e], s_acc[e]);
        } else {
            float* st = stat_out + (bi & 7)*512;
            #pragma unroll
            for (int e = 0; e < 4; ++e) {
                atomicAdd(&st[c0 + d*4 + e],       s_acc[e]);
                atomicAdd(&st[256 + c0 + d*4 + e], q_acc[e]);
            }
        }
    }
}

// BN -> relu(linear) -> BN -> classifier -> log_softmax. One block, 768 thr.
__global__ __launch_bounds__(768) void tail(
                     const void* __restrict__ fc_g,  const void* __restrict__ fc_b,
                     const void* __restrict__ lin_W, const void* __restrict__ lin_b,
                     const void* __restrict__ hid_g, const void* __restrict__ hid_b,
                     const void* __restrict__ cls_W, const void* __restrict__ cls_b,
                     void* __restrict__ out, const float* ws) {
    __shared__ float g1[BB][HH];
    __shared__ float g2[BB][HH];
    __shared__ __hip_bfloat16 Wl[HH*HH];
    __shared__ float logits[BB][10];
    __shared__ float lse[BB];
    int tid = threadIdx.x;
    const int isf = ((const int*)ws)[OFF_FLAG];
    const float* g = ws + OFF_G;   // sums over N; scale by 1/NN
    if (isf) {
        const float* Wp = (const float*)lin_W;
        for (int i = tid; i < HH*HH; i += 768) Wl[i] = __float2bfloat16(Wp[i]);
    } else {
        const __hip_bfloat16* Wp = (const __hip_bfloat16*)lin_W;
        for (int i = tid; i < HH*HH; i += 768) Wl[i] = Wp[i];
    }
    if (tid < HH) {
        float s = 0.f, sq = 0.f;
        for (int b = 0; b < BB; ++b) {
            float v = g[b*HH + tid] * (1.f/NN);
            s += v; sq += v*v;
        }
        float m = s*(1.f/BB), var = sq*(1.f/BB) - m*m;
        float a = ldin(fc_g, tid, isf) * rsqrtf(var + EPSV);
        float c = ldin(fc_b, tid, isf) - m*a;
        for (int b = 0; b < BB; ++b) g1[b][tid] = g[b*HH + tid]*(1.f/NN)*a + c;
    }
    __syncthreads();
    {
        int n = tid % HH, bg = tid / HH;
        float lb = ldin(lin_b, n, isf);
        float a0 = lb, a1 = lb, a2 = lb, a3 = lb;
        int b0 = bg*4;
        for (int k = 0; k < HH; ++k) {
            float wv = bf(Wl[k*HH + n]);
            a0 += g1[b0+0][k]*wv;
            a1 += g1[b0+1][k]*wv;
            a2 += g1[b0+2][k]*wv;
            a3 += g1[b0+3][k]*wv;
        }
        g2[b0+0][n] = fmaxf(a0, 0.f);
        g2[b0+1][n] = fmaxf(a1, 0.f);
        g2[b0+2][n] = fmaxf(a2, 0.f);
        g2[b0+3][n] = fmaxf(a3, 0.f);
    }
    __syncthreads();
    if (tid < HH) {
        float s = 0.f, sq = 0.f;
        for (int b = 0; b < BB; ++b) { float v = g2[b][tid]; s += v; sq += v*v; }
        float m = s*(1.f/BB), var = sq*(1.f/BB) - m*m;
        float a = ldin(hid_g, tid, isf) * rsqrtf(var + EPSV);
        float c = ldin(hid_b, tid, isf) - m*a;
        for (int b = 0; b < BB; ++b) g2[b][tid] = g2[b][tid]*a + c;
    }
    __syncthreads();
    if (tid < BB*10) {
        int b = tid/10, k = tid%10;
        float acc = ldin(cls_b, k, isf);
        for (int h = 0; h < HH; ++h) acc += g2[b][h] * ldin(cls_W, (size_t)h*10 + k, isf);
        logits[b][k] = acc;
    }
    __syncthreads();
    if (tid < BB) {
        float m = -1e30f;
        for (int k = 0; k < 10; ++k) m = fmaxf(m, logits[tid][k]);
        float s = 0.f;
        for (int k = 0; k < 10; ++k) s += expf(logits[tid][k] - m);
        lse[tid] = m + logf(s);
    }
    __syncthreads();
    if (tid < BB*10) {
        int b = tid/10;
        float v = logits[b][tid%10] - lse[b];
        if (isf) ((float*)out)[tid] = v;
        else     ((__hip_bfloat16*)out)[tid] = __float2bfloat16(v);
    }
}

extern "C" void kernel_launch(void* const* d_in, const int* in_sizes, int n_in,
                              void* d_out, int out_size, void* d_ws, size_t ws_size,
                              hipStream_t stream) {
    const void* x       = d_in[0];
    const void* adj     = d_in[1];
    const void* bnf_g   = d_in[2];
    const void* bnf_b   = d_in[3];
    const void* W_feat  = d_in[4];
    const void* bnc_g   = d_in[5];
    const void* bnc_b   = d_in[6];
    const void* convs_W = d_in[7];
    const void* convs_b = d_in[8];
    const void* fc_g    = d_in[9];
    const void* fc_b    = d_in[10];
    const void* lin_W   = d_in[11];
    const void* lin_b   = d_in[12];
    const void* hid_g   = d_in[13];
    const void* hid_b   = d_in[14];
    const void* cls_W   = d_in[15];
    const void* cls_b   = d_in[16];

    float* ws = (float*)d_ws;
    const __hip_bfloat16* WPF = (const __hip_bfloat16*)(ws + OFF_WPF);
    const __hip_bfloat16* WPC = (const __hip_bfloat16*)(ws + OFF_WPC);

    detect_and_zero<<<1, 256, 0, stream>>>((const unsigned int*)adj, ws);
    phase1<<<NROWS + 256, 256, 0, stream>>>(adj, x, ws);
    prep_feat<<<HH, FF, 0, stream>>>(W_feat, bnf_g, bnf_b, ws);
    gemm_mfma<FF, 0><<<NROWS/32, 256, 0, stream>>>(x, WPF, ws + OFF_BF, ws);
    for (int l = 0; l < 3; ++l) {
        prep_conv<<<HH, HH, 0, stream>>>(convs_W, bnc_g, bnc_b, l, ws);
        gemm_mfma<HH, 1><<<NROWS/32, 256, 0, stream>>>(
            (const void*)(ws + OFF_H0), WPC, ws + OFF_BC, ws);
        spmm<<<192, 512, 0, stream>>>(convs_b, l,
            (l < 2) ? stage_h(ws, l + 1) : nullptr, (l == 2) ? 1 : 0, ws);
    }
    tail<<<1, 768, 0, stream>>>(fc_g, fc_b, lin_W, lin_b,
                                hid_g, hid_b, cls_W, cls_b, d_out, ws);
}